// Round 11
// baseline (584.172 us; speedup 1.0000x reference)
//
#include <hip/hip_runtime.h>

// ---------------- dtype helpers ----------------
__device__ __forceinline__ float b2f(unsigned short u) {
  return __uint_as_float(((unsigned)u) << 16);
}
__device__ __forceinline__ unsigned short f2b(float f) {
  unsigned u = __float_as_uint(f);
  return (unsigned short)((u + 0x7FFFu + ((u >> 16) & 1u)) >> 16);
}
// load element i of a tensor that is bf16 (isb=1) or fp32 (isb=0)
__device__ __forceinline__ float gload(const void* p, int i, int isb) {
  return isb ? b2f(((const unsigned short*)p)[i]) : ((const float*)p)[i];
}
// monotone bijection float -> uint32 (order-preserving incl. negatives)
__device__ __forceinline__ unsigned tokey(float f) {
  unsigned u = __float_as_uint(f);
  return u ^ (unsigned)(((int)u >> 31) | 0x80000000u);
}

// ---------------- dtype detector (dataset proven fp32; kept for safety) ----------------
__global__ void k_detect(const void* x, int* flag) {
  int tid = threadIdx.x;  // 1 wave
  unsigned short u = ((const unsigned short*)x)[2 * tid];
  int e = (u >> 7) & 0xFF;
  bool sane = (e >= 100 && e <= 140);
  unsigned long long m = __ballot(sane);
  if (tid == 0) *flag = (__popcll(m) >= 40) ? 1 : 0;
}

// ---------------- k_prep: WtF[i][u] = fc1_w[u][i] * (mask<0.5), f32 transposed ----------------
__global__ __launch_bounds__(256) void k_prep(const void* __restrict__ fc1w,
                                              const void* __restrict__ mraw,
                                              float* __restrict__ WtF,
                                              const int* __restrict__ flag) {
  __shared__ float tile[64][65];
  const int isb = *flag;
  const int i0 = blockIdx.x * 64;  // K index (9216)
  const int u0 = blockIdx.y * 64;  // unit index (1024)
  const int tx = threadIdx.x & 63, ty = threadIdx.x >> 6;
  for (int uu = ty; uu < 64; uu += 4) {
    int gi = (u0 + uu) * 9216 + i0 + tx;
    float wv = gload(fc1w, gi, isb);
    float mv = gload(mraw, gi, isb);
    tile[uu][tx] = (mv < 0.5f) ? wv : 0.0f;
  }
  __syncthreads();
  for (int ii = ty; ii < 64; ii += 4)
    WtF[(i0 + ii) * 1024 + u0 + tx] = tile[tx][ii];
}

// ---------------- k_conv: conv5x5 + pool + radix kwinners (r10-FROZEN) ----------------
// Ladder: r3 204us -> r8 +runlength/-barrier 168 -> r9 4-block LDS 163 ->
// r10 unclamped VGPR(72, no spill) 160us @ VALUBusy 93%. Issue-saturated;
// do not touch (v5/v6: any restructure of the conv loop spills).
__global__ __launch_bounds__(256) void k_conv(const void* __restrict__ x,
                                              const void* __restrict__ c1w_g,
                                              const void* __restrict__ c1b_g,
                                              const void* __restrict__ duty_g,
                                              int2* __restrict__ wpair,
                                              int* __restrict__ wcnt,
                                              const int* __restrict__ flag) {
  // img[784] floats (3136B) unioned with hist2[2][256] (2048B): img is dead
  // after the post-conv __syncthreads; hist writes all come after it.
  __shared__ __align__(16) unsigned char u_imghist[3136];
  __shared__ float cb[64], bcs[64];
  __shared__ __align__(16) float pooled[9216];
  __shared__ unsigned wtot[4];
  __shared__ unsigned selb, selk;
  float* img = (float*)u_imghist;
  unsigned* h2a = (unsigned*)u_imghist;           // hist2[0]
  unsigned* h2b = (unsigned*)(u_imghist + 1024);  // hist2[1]
  const int tid = threadIdx.x;
  const int b = blockIdx.x;
  const int isb = *flag;
  const int lane = tid & 63;
  const int wv_id = tid >> 6;

  for (int i = tid; i < 784; i += 256) img[i] = gload(x, b * 784 + i, isb);
  if (tid < 64) {
    cb[tid] = gload(c1b_g, tid, isb);
    float arg = (float)(400.0 / 9216.0) - gload(duty_g, tid, isb);
    bcs[tid] = (float)exp((double)arg);
  }
  __syncthreads();

  // mapping: c = tid>>2 (64), half = tid&1 (2), pg = (tid>>1)&1 (2) -> ph0 = pg*6
  {
    const int c = tid >> 2;
    const int half = tid & 1;
    const int ph0 = ((tid >> 1) & 1) * 6;
    float w[25];
#pragma unroll
    for (int i = 0; i < 25; ++i) w[i] = gload(c1w_g, c * 25 + i, isb);
    const float bias = cb[c];
    float R[6][16];
#pragma unroll
    for (int r = 0; r < 6; ++r) {
      int ir = 2 * ph0 + r;
#pragma unroll
      for (int q = 0; q < 4; ++q)
        ((float4*)&R[r][0])[q] = ((const float4*)img)[ir * 7 + half * 3 + q];
    }
#pragma unroll
    for (int i = 0; i < 6; ++i) {
      const int ph = ph0 + i;
      float a0[12], a1[12];
#pragma unroll
      for (int j = 0; j < 12; ++j) { a0[j] = 0.f; a1[j] = 0.f; }
      // single sequential fmaf chain per conv cell, k = kw*5 + kh order
      // (kh fastest -- Eigen patch linearization) => bit-exact vs reference
#pragma unroll
      for (int kj = 0; kj < 5; ++kj) {       // kw OUTER
#pragma unroll
        for (int kr = 0; kr < 5; ++kr) {     // kh INNER (fastest)
          float wk = w[kr * 5 + kj];
          const float* r0 = &R[(2 * i + kr) % 6][0];
          const float* r1 = &R[(2 * i + kr + 1) % 6][0];
#pragma unroll
          for (int j = 0; j < 12; ++j) {
            a0[j] = fmaf(r0[j + kj], wk, a0[j]);
            a1[j] = fmaf(r1[j + kj], wk, a1[j]);
          }
        }
      }
      int obase = c * 144 + ph * 12 + half * 6;
#pragma unroll
      for (int q = 0; q < 6; ++q) {
        float m = fmaxf(fmaxf(a0[2 * q], a0[2 * q + 1]),
                        fmaxf(a1[2 * q], a1[2 * q + 1]));
        pooled[obase + q] = m + bias;
      }
      if (i < 5) {  // slide: load img rows 2*ph+6, 2*ph+7 over the two oldest
        int ir0 = 2 * ph + 6, ir1 = 2 * ph + 7;
        float* d0 = &R[(2 * i) % 6][0];
        float* d1 = &R[(2 * i + 1) % 6][0];
#pragma unroll
        for (int q = 0; q < 4; ++q) {
          ((float4*)d0)[q] = ((const float4*)img)[ir0 * 7 + half * 3 + q];
          ((float4*)d1)[q] = ((const float4*)img)[ir1 * 7 + half * 3 + q];
        }
      }
    }
  }
  __syncthreads();  // after this barrier img is DEAD -> its LDS becomes hist2

  // compute this thread's 36 select keys ONCE into registers
  unsigned keys[36];
  {
    const float bcf = bcs[tid >> 2];
#pragma unroll
    for (int e4 = 0; e4 < 9; ++e4) {
      float4 pv = ((float4*)pooled)[tid * 9 + e4];
      keys[4 * e4 + 0] = tokey(pv.x * bcf);
      keys[4 * e4 + 1] = tokey(pv.y * bcf);
      keys[4 * e4 + 2] = tokey(pv.z * bcf);
      keys[4 * e4 + 3] = tokey(pv.w * bcf);
    }
  }

  // radix-select the 400th-largest key; 2 split histograms + shfl suffix scan
  unsigned kfix = 0;
  unsigned kk = 400;
  for (int pass = 3; pass >= 0; --pass) {
    const int shift = pass * 8;
    const unsigned himask = (pass == 3) ? 0u : (0xFFFFFFFFu << (shift + 8));
    h2a[tid] = 0;
    h2b[tid] = 0;
    __syncthreads();
    unsigned* myh = (wv_id < 2) ? h2a : h2b;
    if (pass == 3) {
      // run-length aggregated (all-static indices; scalars only)
      unsigned cbin = keys[0] >> 24, ccnt = 1;
#pragma unroll
      for (int e = 1; e < 36; ++e) {
        unsigned bin = keys[e] >> 24;
        if (bin == cbin) {
          ++ccnt;
        } else {
          atomicAdd(&myh[cbin], ccnt);
          cbin = bin;
          ccnt = 1;
        }
      }
      atomicAdd(&myh[cbin], ccnt);
    } else {
#pragma unroll
      for (int e = 0; e < 36; ++e) {
        unsigned key = keys[e];
        if (((key ^ kfix) & himask) == 0)
          atomicAdd(&myh[(key >> shift) & 255u], 1u);
      }
    }
    __syncthreads();
    unsigned own = h2a[tid] + h2b[tid];
    unsigned v = own;
#pragma unroll
    for (int off = 1; off < 64; off <<= 1) {
      unsigned y = __shfl_down(v, off, 64);
      if (lane + off < 64) v += y;
    }
    if (lane == 0) wtot[wv_id] = v;
    __syncthreads();
#pragma unroll
    for (int w2 = 0; w2 < 4; ++w2)
      if (w2 > wv_id) v += wtot[w2];
    unsigned snext = v - own;
    if (v >= kk && snext < kk) {
      selb = (unsigned)tid;
      selk = kk - snext;
    }
    __syncthreads();
    kfix |= selb << shift;
    kk = selk;
    // (5th barrier removed: next pass's zero->sync orders selb/selk reuse)
  }

  // sorted compaction: per-thread count -> shfl prefix scan -> ordered write.
  // keep ALL with key >= kfix (== boosted >= thr bitwise, ties kept like ref)
  unsigned mycnt = 0;
#pragma unroll
  for (int e = 0; e < 36; ++e) mycnt += (keys[e] >= kfix) ? 1u : 0u;
  unsigned px = mycnt;
#pragma unroll
  for (int off = 1; off < 64; off <<= 1) {
    unsigned y = __shfl_up(px, off, 64);
    if (lane >= off) px += y;
  }
  if (lane == 63) wtot[wv_id] = px;
  __syncthreads();
  unsigned base = 0;
#pragma unroll
  for (int w2 = 0; w2 < 4; ++w2)
    if (w2 < wv_id) base += wtot[w2];
  int pos = (int)(base + px - mycnt);  // exclusive prefix
  for (int e = 0; e < 36; ++e) {
    if (keys[e] >= kfix) {
      int o = tid * 36 + e;
      if (pos < 512)
        wpair[b * 512 + pos] = make_int2(__float_as_int(pooled[o]), o << 12);
      ++pos;
    }
  }
  if (tid == 0) {
    unsigned tot = wtot[0] + wtot[1] + wtot[2] + wtot[3];
    wcnt[b] = (int)(tot < 512u ? tot : 512u);
  }
}

// ---------------- k_fc1: XCD-sliced sparse fc1 gather (r3-proven form, FROZEN) ----------------
// Structure optimum per three convergent experiments: scalar s_load (+10us,
// r2), float2 2-unit lanes (+55us/dispatch, r7 -- halved thread count halved
// MLP). Keep: max threads, 1 unit/lane, LDS-staged winner list, 8-pair int4
// unroll. Ascending-w single f32 fmaf chain per unit => bit-identical h.
// v11: back to ONE full-grid dispatch (2x135us characterized; saves a gap).
__global__ __launch_bounds__(128) void k_fc1(const float* __restrict__ WtF,
                                             const int2* __restrict__ wpair,
                                             const int* __restrict__ wcnt,
                                             const void* __restrict__ fc1b,
                                             float* __restrict__ h,
                                             const int* __restrict__ flag) {
  __shared__ __align__(16) int2 wl[512];
  const int tid = threadIdx.x;  // 0..127
  const int img = blockIdx.x >> 3;
  const int slice = blockIdx.x & 7;
  const int isb = *flag;
  const int cnt = wcnt[img];
  const int2* __restrict__ wp = wpair + img * 512;
  for (int i = tid; i < cnt; i += 128) wl[i] = wp[i];
  __syncthreads();
  const int u = (slice << 7) + tid;
  const char* __restrict__ Wb = (const char*)WtF + (unsigned)u * 4u;
  const int4* wl4 = (const int4*)wl;  // 2 pairs per int4, 16B-aligned
  float acc = 0.f;
  int w = 0;
  for (; w + 8 <= cnt; w += 8) {
    const int b4 = w >> 1;
    int4 q0 = wl4[b4 + 0];
    int4 q1 = wl4[b4 + 1];
    int4 q2 = wl4[b4 + 2];
    int4 q3 = wl4[b4 + 3];
    acc = fmaf(__int_as_float(q0.x), *(const float*)(Wb + (unsigned)q0.y), acc);
    acc = fmaf(__int_as_float(q0.z), *(const float*)(Wb + (unsigned)q0.w), acc);
    acc = fmaf(__int_as_float(q1.x), *(const float*)(Wb + (unsigned)q1.y), acc);
    acc = fmaf(__int_as_float(q1.z), *(const float*)(Wb + (unsigned)q1.w), acc);
    acc = fmaf(__int_as_float(q2.x), *(const float*)(Wb + (unsigned)q2.y), acc);
    acc = fmaf(__int_as_float(q2.z), *(const float*)(Wb + (unsigned)q2.w), acc);
    acc = fmaf(__int_as_float(q3.x), *(const float*)(Wb + (unsigned)q3.y), acc);
    acc = fmaf(__int_as_float(q3.z), *(const float*)(Wb + (unsigned)q3.w), acc);
  }
  for (; w < cnt; ++w) {
    int2 p = wl[w];
    acc = fmaf(__int_as_float(p.x), *(const float*)(Wb + (unsigned)p.y), acc);
  }
  h[img * 1024 + u] = acc + gload(fc1b, u, isb);
}

// ---------------- k_boost: fc boost factors computed ONCE ----------------
__global__ __launch_bounds__(256) void k_boost(const void* __restrict__ dutyfc,
                                               float* __restrict__ bf,
                                               const int* __restrict__ flag) {
  const int u = blockIdx.x * 256 + threadIdx.x;
  const int isb = *flag;
  if (u < 1024)
    bf[u] = (float)exp((double)(0.09765625f - gload(dutyfc, u, isb)));
}

// ---------------- k_sel: kwinners(k=100, >=thr) + f64 fc2 + log_softmax ----------------
// v11: (a) HALF-GRID x2 (row_base) for rocprof visibility -- is k_sel the
// missing ~120us or is it launch gaps? (b) the serial tid==0 softmax tail
// parallelized: 10 independent f64 exp() run on tid<10 concurrently (each
// ~300-500cyc software sequence; was serial while 255 threads waited), then
// tid==0 sums in the SAME ascending-c order (order preserved => bit-exact)
// and takes the single log.
__global__ __launch_bounds__(256) void k_sel(const float* __restrict__ h,
                                             const float* __restrict__ bf,
                                             const void* __restrict__ fc2w,
                                             const void* __restrict__ fc2b,
                                             void* __restrict__ out,
                                             const int* __restrict__ flag,
                                             int row_base) {
  __shared__ unsigned hist4[4][256];
  __shared__ unsigned wtot[4];
  __shared__ unsigned selb, selk;
  __shared__ double lg[10];
  __shared__ double eex[10];
  __shared__ double mred[2];
  const int tid = threadIdx.x;
  const int row = row_base + blockIdx.x;
  const int isb = *flag;
  const int lane = tid & 63;
  const int wv_id = tid >> 6;
  if (tid < 10) lg[tid] = (double)gload(fc2b, tid, isb);
  __syncthreads();

  const int u0 = 2 * tid, u1 = 2 * tid + 1, u2 = 512 + 2 * tid, u3 = 513 + 2 * tid;
  float2 hlo = ((const float2*)(h + row * 1024))[tid];
  float2 hhi = ((const float2*)(h + row * 1024 + 512))[tid];
  float h0 = hlo.x, h1 = hlo.y, h2 = hhi.x, h3 = hhi.y;
  float2 blo = ((const float2*)bf)[tid];
  float2 bhi = ((const float2*)(bf + 512))[tid];
  unsigned k0 = tokey(h0 * blo.x);
  unsigned k1 = tokey(h1 * blo.y);
  unsigned k2 = tokey(h2 * bhi.x);
  unsigned k3 = tokey(h3 * bhi.y);

  unsigned kfix = 0;
  unsigned kk = 100;
  for (int pass = 3; pass >= 0; --pass) {
    const int shift = pass * 8;
    const unsigned himask = (pass == 3) ? 0u : (0xFFFFFFFFu << (shift + 8));
#pragma unroll
    for (int w2 = 0; w2 < 4; ++w2) hist4[w2][tid] = 0;
    __syncthreads();
    unsigned* myh = hist4[wv_id];
    if (((k0 ^ kfix) & himask) == 0) atomicAdd(&myh[(k0 >> shift) & 255u], 1u);
    if (((k1 ^ kfix) & himask) == 0) atomicAdd(&myh[(k1 >> shift) & 255u], 1u);
    if (((k2 ^ kfix) & himask) == 0) atomicAdd(&myh[(k2 >> shift) & 255u], 1u);
    if (((k3 ^ kfix) & himask) == 0) atomicAdd(&myh[(k3 >> shift) & 255u], 1u);
    __syncthreads();
    unsigned own = hist4[0][tid] + hist4[1][tid] + hist4[2][tid] + hist4[3][tid];
    unsigned v = own;
#pragma unroll
    for (int off = 1; off < 64; off <<= 1) {
      unsigned y = __shfl_down(v, off, 64);
      if (lane + off < 64) v += y;
    }
    if (lane == 0) wtot[wv_id] = v;
    __syncthreads();
#pragma unroll
    for (int w2 = 0; w2 < 4; ++w2)
      if (w2 > wv_id) v += wtot[w2];
    unsigned snext = v - own;
    if (v >= kk && snext < kk) {
      selb = (unsigned)tid;
      selk = kk - snext;
    }
    __syncthreads();
    kfix |= selb << shift;
    kk = selk;
    // (5th barrier removed; next pass's zero->sync orders reuse)
  }
  bool kp0 = k0 >= kfix, kp1 = k1 >= kfix, kp2 = k2 >= kfix, kp3 = k3 >= kfix;

  double part[10];
#pragma unroll
  for (int c = 0; c < 10; ++c) part[c] = 0.0;
  if (kp0) {
#pragma unroll
    for (int c = 0; c < 10; ++c) part[c] = fma((double)h0, (double)gload(fc2w, c * 1024 + u0, isb), part[c]);
  }
  if (kp1) {
#pragma unroll
    for (int c = 0; c < 10; ++c) part[c] = fma((double)h1, (double)gload(fc2w, c * 1024 + u1, isb), part[c]);
  }
  if (kp2) {
#pragma unroll
    for (int c = 0; c < 10; ++c) part[c] = fma((double)h2, (double)gload(fc2w, c * 1024 + u2, isb), part[c]);
  }
  if (kp3) {
#pragma unroll
    for (int c = 0; c < 10; ++c) part[c] = fma((double)h3, (double)gload(fc2w, c * 1024 + u3, isb), part[c]);
  }
#pragma unroll
  for (int c = 0; c < 10; ++c) {
    double p = part[c];
    for (int off = 32; off > 0; off >>= 1) p += __shfl_xor(p, off);
    if ((tid & 63) == 0) atomicAdd(&lg[c], p);
  }
  __syncthreads();
  if (tid == 0) {
    double m = lg[0];
#pragma unroll
    for (int c = 1; c < 10; ++c) m = lg[c] > m ? lg[c] : m;
    mred[0] = m;
  }
  __syncthreads();
  if (tid < 10) eex[tid] = exp(lg[tid] - mred[0]);  // 10 exps in PARALLEL
  __syncthreads();
  if (tid == 0) {
    double sum = 0.0;
#pragma unroll
    for (int c = 0; c < 10; ++c) sum += eex[c];  // same ascending order => bit-exact
    mred[1] = log(sum);
  }
  __syncthreads();
  if (tid < 10) {
    double o = lg[tid] - mred[0] - mred[1];
    if (isb)
      ((unsigned short*)out)[row * 10 + tid] = f2b((float)o);
    else
      ((float*)out)[row * 10 + tid] = (float)o;
  }
}

// ---------------- launch ----------------
extern "C" void kernel_launch(void* const* d_in, const int* in_sizes, int n_in,
                              void* d_out, int out_size, void* d_ws, size_t ws_size,
                              hipStream_t stream) {
  // ws layout (bytes):
  //   WtF   : 9216*1024*4 = 37,748,736  @ 0   (reused as bf[1024] after k_fc1)
  //   wpair : 4096*512*8  = 16,777,216  @ 37,748,736
  //   wcnt  : 4096*4      =     16,384  @ 54,525,952
  //   h     : 4096*1024*4 = 16,777,216  @ 54,542,336
  //   flag  : 4                         @ 71,319,552
  char* ws = (char*)d_ws;
  float* WtF = (float*)ws;
  int2* wpair = (int2*)(ws + 37748736);
  int* wcnt = (int*)(ws + 54525952);
  float* h = (float*)(ws + 54542336);
  int* flag = (int*)(ws + 71319552);
  float* bf = WtF;  // WtF region is dead after k_fc1

  k_detect<<<1, 64, 0, stream>>>(d_in[0], flag);
  k_prep<<<dim3(144, 16), 256, 0, stream>>>(d_in[4], d_in[5], WtF, flag);
  k_conv<<<4096, 256, 0, stream>>>(d_in[0], d_in[1], d_in[2], d_in[3],
                                   wpair, wcnt, flag);
  k_fc1<<<4096 * 8, 128, 0, stream>>>(WtF, wpair, wcnt, d_in[6], h, flag);
  k_boost<<<4, 256, 0, stream>>>(d_in[7], bf, flag);
  k_sel<<<2048, 256, 0, stream>>>(h, bf, d_in[8], d_in[9], d_out, flag, 0);
  k_sel<<<2048, 256, 0, stream>>>(h, bf, d_in[8], d_in[9], d_out, flag, 2048);
}

// Round 12
// 564.686 us; speedup vs baseline: 1.0345x; 1.0345x over previous
//
#include <hip/hip_runtime.h>

// ---------------- dtype helpers ----------------
__device__ __forceinline__ float b2f(unsigned short u) {
  return __uint_as_float(((unsigned)u) << 16);
}
__device__ __forceinline__ unsigned short f2b(float f) {
  unsigned u = __float_as_uint(f);
  return (unsigned short)((u + 0x7FFFu + ((u >> 16) & 1u)) >> 16);
}
// load element i of a tensor that is bf16 (isb=1) or fp32 (isb=0)
__device__ __forceinline__ float gload(const void* p, int i, int isb) {
  return isb ? b2f(((const unsigned short*)p)[i]) : ((const float*)p)[i];
}
// monotone bijection float -> uint32 (order-preserving incl. negatives)
__device__ __forceinline__ unsigned tokey(float f) {
  unsigned u = __float_as_uint(f);
  return u ^ (unsigned)(((int)u >> 31) | 0x80000000u);
}

// ---------------- dtype detector (dataset proven fp32; kept for safety) ----------------
__global__ void k_detect(const void* x, int* flag) {
  int tid = threadIdx.x;  // 1 wave
  unsigned short u = ((const unsigned short*)x)[2 * tid];
  int e = (u >> 7) & 0xFF;
  bool sane = (e >= 100 && e <= 140);
  unsigned long long m = __ballot(sane);
  if (tid == 0) *flag = (__popcll(m) >= 40) ? 1 : 0;
}

// ---------------- k_prep: WtF[i][u] = fc1_w[u][i] * (mask<0.5), f32 transposed ----------------
__global__ __launch_bounds__(256) void k_prep(const void* __restrict__ fc1w,
                                              const void* __restrict__ mraw,
                                              float* __restrict__ WtF,
                                              const int* __restrict__ flag) {
  __shared__ float tile[64][65];
  const int isb = *flag;
  const int i0 = blockIdx.x * 64;  // K index (9216)
  const int u0 = blockIdx.y * 64;  // unit index (1024)
  const int tx = threadIdx.x & 63, ty = threadIdx.x >> 6;
  for (int uu = ty; uu < 64; uu += 4) {
    int gi = (u0 + uu) * 9216 + i0 + tx;
    float wv = gload(fc1w, gi, isb);
    float mv = gload(mraw, gi, isb);
    tile[uu][tx] = (mv < 0.5f) ? wv : 0.0f;
  }
  __syncthreads();
  for (int ii = ty; ii < 64; ii += 4)
    WtF[(i0 + ii) * 1024 + u0 + tx] = tile[tx][ii];
}

// ---------------- k_conv: conv5x5 + pool + radix kwinners (r10-FROZEN) ----------------
// Ladder: r3 204us -> r8 +runlength/-barrier 168 -> r9 4-block LDS 163 ->
// r10 unclamped VGPR(72, no spill) 160us @ VALUBusy 93%. Issue-saturated;
// do not touch (v5/v6: any restructure of the conv loop spills).
__global__ __launch_bounds__(256) void k_conv(const void* __restrict__ x,
                                              const void* __restrict__ c1w_g,
                                              const void* __restrict__ c1b_g,
                                              const void* __restrict__ duty_g,
                                              int2* __restrict__ wpair,
                                              int* __restrict__ wcnt,
                                              const int* __restrict__ flag) {
  // img[784] floats (3136B) unioned with hist2[2][256] (2048B): img is dead
  // after the post-conv __syncthreads; hist writes all come after it.
  __shared__ __align__(16) unsigned char u_imghist[3136];
  __shared__ float cb[64], bcs[64];
  __shared__ __align__(16) float pooled[9216];
  __shared__ unsigned wtot[4];
  __shared__ unsigned selb, selk;
  float* img = (float*)u_imghist;
  unsigned* h2a = (unsigned*)u_imghist;           // hist2[0]
  unsigned* h2b = (unsigned*)(u_imghist + 1024);  // hist2[1]
  const int tid = threadIdx.x;
  const int b = blockIdx.x;
  const int isb = *flag;
  const int lane = tid & 63;
  const int wv_id = tid >> 6;

  for (int i = tid; i < 784; i += 256) img[i] = gload(x, b * 784 + i, isb);
  if (tid < 64) {
    cb[tid] = gload(c1b_g, tid, isb);
    float arg = (float)(400.0 / 9216.0) - gload(duty_g, tid, isb);
    bcs[tid] = (float)exp((double)arg);
  }
  __syncthreads();

  // mapping: c = tid>>2 (64), half = tid&1 (2), pg = (tid>>1)&1 (2) -> ph0 = pg*6
  {
    const int c = tid >> 2;
    const int half = tid & 1;
    const int ph0 = ((tid >> 1) & 1) * 6;
    float w[25];
#pragma unroll
    for (int i = 0; i < 25; ++i) w[i] = gload(c1w_g, c * 25 + i, isb);
    const float bias = cb[c];
    float R[6][16];
#pragma unroll
    for (int r = 0; r < 6; ++r) {
      int ir = 2 * ph0 + r;
#pragma unroll
      for (int q = 0; q < 4; ++q)
        ((float4*)&R[r][0])[q] = ((const float4*)img)[ir * 7 + half * 3 + q];
    }
#pragma unroll
    for (int i = 0; i < 6; ++i) {
      const int ph = ph0 + i;
      float a0[12], a1[12];
#pragma unroll
      for (int j = 0; j < 12; ++j) { a0[j] = 0.f; a1[j] = 0.f; }
      // single sequential fmaf chain per conv cell, k = kw*5 + kh order
      // (kh fastest -- Eigen patch linearization) => bit-exact vs reference
#pragma unroll
      for (int kj = 0; kj < 5; ++kj) {       // kw OUTER
#pragma unroll
        for (int kr = 0; kr < 5; ++kr) {     // kh INNER (fastest)
          float wk = w[kr * 5 + kj];
          const float* r0 = &R[(2 * i + kr) % 6][0];
          const float* r1 = &R[(2 * i + kr + 1) % 6][0];
#pragma unroll
          for (int j = 0; j < 12; ++j) {
            a0[j] = fmaf(r0[j + kj], wk, a0[j]);
            a1[j] = fmaf(r1[j + kj], wk, a1[j]);
          }
        }
      }
      int obase = c * 144 + ph * 12 + half * 6;
#pragma unroll
      for (int q = 0; q < 6; ++q) {
        float m = fmaxf(fmaxf(a0[2 * q], a0[2 * q + 1]),
                        fmaxf(a1[2 * q], a1[2 * q + 1]));
        pooled[obase + q] = m + bias;
      }
      if (i < 5) {  // slide: load img rows 2*ph+6, 2*ph+7 over the two oldest
        int ir0 = 2 * ph + 6, ir1 = 2 * ph + 7;
        float* d0 = &R[(2 * i) % 6][0];
        float* d1 = &R[(2 * i + 1) % 6][0];
#pragma unroll
        for (int q = 0; q < 4; ++q) {
          ((float4*)d0)[q] = ((const float4*)img)[ir0 * 7 + half * 3 + q];
          ((float4*)d1)[q] = ((const float4*)img)[ir1 * 7 + half * 3 + q];
        }
      }
    }
  }
  __syncthreads();  // after this barrier img is DEAD -> its LDS becomes hist2

  // compute this thread's 36 select keys ONCE into registers
  unsigned keys[36];
  {
    const float bcf = bcs[tid >> 2];
#pragma unroll
    for (int e4 = 0; e4 < 9; ++e4) {
      float4 pv = ((float4*)pooled)[tid * 9 + e4];
      keys[4 * e4 + 0] = tokey(pv.x * bcf);
      keys[4 * e4 + 1] = tokey(pv.y * bcf);
      keys[4 * e4 + 2] = tokey(pv.z * bcf);
      keys[4 * e4 + 3] = tokey(pv.w * bcf);
    }
  }

  // radix-select the 400th-largest key; 2 split histograms + shfl suffix scan
  unsigned kfix = 0;
  unsigned kk = 400;
  for (int pass = 3; pass >= 0; --pass) {
    const int shift = pass * 8;
    const unsigned himask = (pass == 3) ? 0u : (0xFFFFFFFFu << (shift + 8));
    h2a[tid] = 0;
    h2b[tid] = 0;
    __syncthreads();
    unsigned* myh = (wv_id < 2) ? h2a : h2b;
    if (pass == 3) {
      // run-length aggregated (all-static indices; scalars only)
      unsigned cbin = keys[0] >> 24, ccnt = 1;
#pragma unroll
      for (int e = 1; e < 36; ++e) {
        unsigned bin = keys[e] >> 24;
        if (bin == cbin) {
          ++ccnt;
        } else {
          atomicAdd(&myh[cbin], ccnt);
          cbin = bin;
          ccnt = 1;
        }
      }
      atomicAdd(&myh[cbin], ccnt);
    } else {
#pragma unroll
      for (int e = 0; e < 36; ++e) {
        unsigned key = keys[e];
        if (((key ^ kfix) & himask) == 0)
          atomicAdd(&myh[(key >> shift) & 255u], 1u);
      }
    }
    __syncthreads();
    unsigned own = h2a[tid] + h2b[tid];
    unsigned v = own;
#pragma unroll
    for (int off = 1; off < 64; off <<= 1) {
      unsigned y = __shfl_down(v, off, 64);
      if (lane + off < 64) v += y;
    }
    if (lane == 0) wtot[wv_id] = v;
    __syncthreads();
#pragma unroll
    for (int w2 = 0; w2 < 4; ++w2)
      if (w2 > wv_id) v += wtot[w2];
    unsigned snext = v - own;
    if (v >= kk && snext < kk) {
      selb = (unsigned)tid;
      selk = kk - snext;
    }
    __syncthreads();
    kfix |= selb << shift;
    kk = selk;
    // (5th barrier removed: next pass's zero->sync orders selb/selk reuse)
  }

  // sorted compaction: per-thread count -> shfl prefix scan -> ordered write.
  // keep ALL with key >= kfix (== boosted >= thr bitwise, ties kept like ref)
  unsigned mycnt = 0;
#pragma unroll
  for (int e = 0; e < 36; ++e) mycnt += (keys[e] >= kfix) ? 1u : 0u;
  unsigned px = mycnt;
#pragma unroll
  for (int off = 1; off < 64; off <<= 1) {
    unsigned y = __shfl_up(px, off, 64);
    if (lane >= off) px += y;
  }
  if (lane == 63) wtot[wv_id] = px;
  __syncthreads();
  unsigned base = 0;
#pragma unroll
  for (int w2 = 0; w2 < 4; ++w2)
    if (w2 < wv_id) base += wtot[w2];
  int pos = (int)(base + px - mycnt);  // exclusive prefix
  for (int e = 0; e < 36; ++e) {
    if (keys[e] >= kfix) {
      int o = tid * 36 + e;
      if (pos < 512)
        wpair[b * 512 + pos] = make_int2(__float_as_int(pooled[o]), o << 12);
      ++pos;
    }
  }
  if (tid == 0) {
    unsigned tot = wtot[0] + wtot[1] + wtot[2] + wtot[3];
    wcnt[b] = (int)(tot < 512u ? tot : 512u);
  }
}

// ---------------- k_fc1: XCD-sliced sparse fc1 gather (r3-proven form, FROZEN) ----------------
__global__ __launch_bounds__(128) void k_fc1(const float* __restrict__ WtF,
                                             const int2* __restrict__ wpair,
                                             const int* __restrict__ wcnt,
                                             const void* __restrict__ fc1b,
                                             float* __restrict__ h,
                                             const int* __restrict__ flag) {
  __shared__ __align__(16) int2 wl[512];
  const int tid = threadIdx.x;  // 0..127
  const int img = blockIdx.x >> 3;
  const int slice = blockIdx.x & 7;
  const int isb = *flag;
  const int cnt = wcnt[img];
  const int2* __restrict__ wp = wpair + img * 512;
  for (int i = tid; i < cnt; i += 128) wl[i] = wp[i];
  __syncthreads();
  const int u = (slice << 7) + tid;
  const char* __restrict__ Wb = (const char*)WtF + (unsigned)u * 4u;
  const int4* wl4 = (const int4*)wl;  // 2 pairs per int4, 16B-aligned
  float acc = 0.f;
  int w = 0;
  for (; w + 8 <= cnt; w += 8) {
    const int b4 = w >> 1;
    int4 q0 = wl4[b4 + 0];
    int4 q1 = wl4[b4 + 1];
    int4 q2 = wl4[b4 + 2];
    int4 q3 = wl4[b4 + 3];
    acc = fmaf(__int_as_float(q0.x), *(const float*)(Wb + (unsigned)q0.y), acc);
    acc = fmaf(__int_as_float(q0.z), *(const float*)(Wb + (unsigned)q0.w), acc);
    acc = fmaf(__int_as_float(q1.x), *(const float*)(Wb + (unsigned)q1.y), acc);
    acc = fmaf(__int_as_float(q1.z), *(const float*)(Wb + (unsigned)q1.w), acc);
    acc = fmaf(__int_as_float(q2.x), *(const float*)(Wb + (unsigned)q2.y), acc);
    acc = fmaf(__int_as_float(q2.z), *(const float*)(Wb + (unsigned)q2.w), acc);
    acc = fmaf(__int_as_float(q3.x), *(const float*)(Wb + (unsigned)q3.y), acc);
    acc = fmaf(__int_as_float(q3.z), *(const float*)(Wb + (unsigned)q3.w), acc);
  }
  for (; w < cnt; ++w) {
    int2 p = wl[w];
    acc = fmaf(__int_as_float(p.x), *(const float*)(Wb + (unsigned)p.y), acc);
  }
  h[img * 1024 + u] = acc + gload(fc1b, u, isb);
}

// ---------------- k_boost: fc boost factors computed ONCE ----------------
__global__ __launch_bounds__(256) void k_boost(const void* __restrict__ dutyfc,
                                               float* __restrict__ bf,
                                               const int* __restrict__ flag) {
  const int u = blockIdx.x * 256 + threadIdx.x;
  const int isb = *flag;
  if (u < 1024)
    bf[u] = (float)exp((double)(0.09765625f - gload(dutyfc, u, isb)));
}

// ---------------- k_sel v12: ONE ROW PER WAVE, zero barriers ----------------
// r11 ledger: k_sel ~115us total but issue-work est. only ~5us -> latency-
// bound on its ~22 block-wide barriers. v12: 4 rows/block, 1 row/WAVE.
// Wave-private LDS hist (1KB/wave, disjoint) -> zero __syncthreads: CDNA
// waves are lockstep and per-wave DS ops execute in order; volatile readback
// stops compiler caching. 256-bin suffix scan = shfl lane-scan + in-lane
// tails (4 bins/lane); threshold bin via ballot+shfl broadcast. fc2 reduce:
// row is wave-local -> butterfly only, no LDS combine. Softmax tail: static
// select chain (no runtime indexing -> no scratch), parallel exps lanes<10,
// ordered 10-shfl sum. Radix counts order-independent => identical kfix;
// fc2 f64 association changes ~1e-14 rel (prior LDS-atomic order was already
// nondeterministic at absmax 0.0).
__global__ __launch_bounds__(256) void k_sel(const float* __restrict__ h,
                                             const float* __restrict__ bf,
                                             const void* __restrict__ fc2w,
                                             const void* __restrict__ fc2b,
                                             void* __restrict__ out,
                                             const int* __restrict__ flag) {
  __shared__ __align__(16) unsigned whist[4][256];
  const int tid = threadIdx.x;
  const int lane = tid & 63;
  const int wv = tid >> 6;
  const int row = blockIdx.x * 4 + wv;
  const int isb = *flag;
  unsigned* hist = whist[wv];
  volatile unsigned* vhist = whist[wv];

  // 16 units/lane, u = j*64 + lane (coalesced); keys in registers
  float hv[16];
  unsigned keys[16];
#pragma unroll
  for (int j = 0; j < 16; ++j) {
    float xv = h[row * 1024 + j * 64 + lane];
    hv[j] = xv;
    keys[j] = tokey(xv * bf[j * 64 + lane]);
  }

  // barrier-free radix select: 100th largest of the wave's 1024 keys
  unsigned kfix = 0, kk = 100;
  for (int pass = 3; pass >= 0; --pass) {
    const int shift = pass * 8;
    const unsigned himask = (pass == 3) ? 0u : (0xFFFFFFFFu << (shift + 8));
    ((uint4*)hist)[lane] = make_uint4(0u, 0u, 0u, 0u);  // 4 bins/lane zeroed
    __builtin_amdgcn_sched_barrier(0);
#pragma unroll
    for (int j = 0; j < 16; ++j) {
      if (((keys[j] ^ kfix) & himask) == 0)
        atomicAdd(&hist[(keys[j] >> shift) & 255u], 1u);
    }
    __builtin_amdgcn_sched_barrier(0);
    unsigned o0 = vhist[4 * lane + 0];
    unsigned o1 = vhist[4 * lane + 1];
    unsigned o2 = vhist[4 * lane + 2];
    unsigned o3 = vhist[4 * lane + 3];
    unsigned lsum = o0 + o1 + o2 + o3;
    unsigned v = lsum;
#pragma unroll
    for (int off = 1; off < 64; off <<= 1) {
      unsigned y = __shfl_down(v, off, 64);
      if (lane + off < 64) v += y;
    }
    const unsigned after = v - lsum;  // sum over lanes > lane
    const unsigned t3 = o3;
    const unsigned t2 = o2 + t3;
    const unsigned t1 = o1 + t2;
    const unsigned t0 = o0 + t1;
    // S(4l+k) = after + t_k ; S(4l+k+1) = after + t_{k+1} (t4 = 0)
    unsigned candb = 0, candk = 0;
    bool found = false;
    const unsigned S0 = after + t0, S1 = after + t1, S2 = after + t2,
                   S3 = after + t3, S4 = after;
    if (S0 >= kk && S1 < kk) { candb = 4u * lane + 0u; candk = kk - S1; found = true; }
    else if (S1 >= kk && S2 < kk) { candb = 4u * lane + 1u; candk = kk - S2; found = true; }
    else if (S2 >= kk && S3 < kk) { candb = 4u * lane + 2u; candk = kk - S3; found = true; }
    else if (S3 >= kk && S4 < kk) { candb = 4u * lane + 3u; candk = kk - S4; found = true; }
    unsigned long long msk = __ballot(found);
    int src = __ffsll((unsigned long long)msk) - 1;  // exactly one bin matches
    candb = __shfl(candb, src, 64);
    candk = __shfl(candk, src, 64);
    kfix |= candb << shift;
    kk = candk;
  }

  // fc2 on kept units (f64), wave butterfly reduce
  double part[10];
#pragma unroll
  for (int c = 0; c < 10; ++c) part[c] = 0.0;
#pragma unroll
  for (int j = 0; j < 16; ++j) {
    if (keys[j] >= kfix) {
      const int u = j * 64 + lane;
      const double hx = (double)hv[j];
#pragma unroll
      for (int c = 0; c < 10; ++c)
        part[c] = fma(hx, (double)gload(fc2w, c * 1024 + u, isb), part[c]);
    }
  }
#pragma unroll
  for (int c = 0; c < 10; ++c) {
    double p = part[c];
#pragma unroll
    for (int off = 32; off > 0; off >>= 1) p += __shfl_xor(p, off);
    part[c] = p + (double)gload(fc2b, c, isb);
  }

  // log_softmax (f64), wave-local; static select chain for per-lane value
  double m = part[0];
#pragma unroll
  for (int c = 1; c < 10; ++c) m = part[c] > m ? part[c] : m;
  double mv = part[0];
#pragma unroll
  for (int c = 1; c < 10; ++c)
    if (lane == c) mv = part[c];
  double e = (lane < 10) ? exp(mv - m) : 0.0;  // 10 exps in parallel
  double sum = 0.0;
#pragma unroll
  for (int c = 0; c < 10; ++c) sum += __shfl(e, c, 64);  // ascending order
  double logs = log(sum);
  if (lane < 10) {
    double o = mv - m - logs;
    if (isb)
      ((unsigned short*)out)[row * 10 + lane] = f2b((float)o);
    else
      ((float*)out)[row * 10 + lane] = (float)o;
  }
}

// ---------------- launch ----------------
extern "C" void kernel_launch(void* const* d_in, const int* in_sizes, int n_in,
                              void* d_out, int out_size, void* d_ws, size_t ws_size,
                              hipStream_t stream) {
  // ws layout (bytes):
  //   WtF   : 9216*1024*4 = 37,748,736  @ 0   (reused as bf[1024] after k_fc1)
  //   wpair : 4096*512*8  = 16,777,216  @ 37,748,736
  //   wcnt  : 4096*4      =     16,384  @ 54,525,952
  //   h     : 4096*1024*4 = 16,777,216  @ 54,542,336
  //   flag  : 4                         @ 71,319,552
  char* ws = (char*)d_ws;
  float* WtF = (float*)ws;
  int2* wpair = (int2*)(ws + 37748736);
  int* wcnt = (int*)(ws + 54525952);
  float* h = (float*)(ws + 54542336);
  int* flag = (int*)(ws + 71319552);
  float* bf = WtF;  // WtF region is dead after k_fc1

  k_detect<<<1, 64, 0, stream>>>(d_in[0], flag);
  k_prep<<<dim3(144, 16), 256, 0, stream>>>(d_in[4], d_in[5], WtF, flag);
  k_conv<<<4096, 256, 0, stream>>>(d_in[0], d_in[1], d_in[2], d_in[3],
                                   wpair, wcnt, flag);
  k_fc1<<<4096 * 8, 128, 0, stream>>>(WtF, wpair, wcnt, d_in[6], h, flag);
  k_boost<<<4, 256, 0, stream>>>(d_in[7], bf, flag);
  k_sel<<<1024, 256, 0, stream>>>(h, bf, d_in[8], d_in[9], d_out, flag);
}

// Round 13
// 555.905 us; speedup vs baseline: 1.0508x; 1.0158x over previous
//
#include <hip/hip_runtime.h>

// ---------------- dtype helpers ----------------
__device__ __forceinline__ float b2f(unsigned short u) {
  return __uint_as_float(((unsigned)u) << 16);
}
__device__ __forceinline__ unsigned short f2b(float f) {
  unsigned u = __float_as_uint(f);
  return (unsigned short)((u + 0x7FFFu + ((u >> 16) & 1u)) >> 16);
}
// load element i of a tensor that is bf16 (isb=1) or fp32 (isb=0)
__device__ __forceinline__ float gload(const void* p, int i, int isb) {
  return isb ? b2f(((const unsigned short*)p)[i]) : ((const float*)p)[i];
}
// monotone bijection float -> uint32 (order-preserving incl. negatives)
__device__ __forceinline__ unsigned tokey(float f) {
  unsigned u = __float_as_uint(f);
  return u ^ (unsigned)(((int)u >> 31) | 0x80000000u);
}

// ---------------- dtype detector (dataset proven fp32; kept for safety) ----------------
__global__ void k_detect(const void* x, int* flag) {
  int tid = threadIdx.x;  // 1 wave
  unsigned short u = ((const unsigned short*)x)[2 * tid];
  int e = (u >> 7) & 0xFF;
  bool sane = (e >= 100 && e <= 140);
  unsigned long long m = __ballot(sane);
  if (tid == 0) *flag = (__popcll(m) >= 40) ? 1 : 0;
}

// ---------------- k_prep: WtF[i][u] = fc1_w[u][i] * (mask<0.5), f32 transposed ----------------
__global__ __launch_bounds__(256) void k_prep(const void* __restrict__ fc1w,
                                              const void* __restrict__ mraw,
                                              float* __restrict__ WtF,
                                              const int* __restrict__ flag) {
  __shared__ float tile[64][65];
  const int isb = *flag;
  const int i0 = blockIdx.x * 64;  // K index (9216)
  const int u0 = blockIdx.y * 64;  // unit index (1024)
  const int tx = threadIdx.x & 63, ty = threadIdx.x >> 6;
  for (int uu = ty; uu < 64; uu += 4) {
    int gi = (u0 + uu) * 9216 + i0 + tx;
    float wv = gload(fc1w, gi, isb);
    float mv = gload(mraw, gi, isb);
    tile[uu][tx] = (mv < 0.5f) ? wv : 0.0f;
  }
  __syncthreads();
  for (int ii = ty; ii < 64; ii += 4)
    WtF[(i0 + ii) * 1024 + u0 + tx] = tile[tx][ii];
}

// ---------------- k_conv: conv5x5 + pool + radix kwinners (r10-FROZEN) ----------------
// Ladder: r3 204us -> r8 +runlength/-barrier 168 -> r9 4-block LDS 163 ->
// r10 unclamped VGPR(72, no spill) 160us @ VALUBusy 93%. Issue-saturated;
// do not touch (v5/v6: any restructure of the conv loop spills).
__global__ __launch_bounds__(256) void k_conv(const void* __restrict__ x,
                                              const void* __restrict__ c1w_g,
                                              const void* __restrict__ c1b_g,
                                              const void* __restrict__ duty_g,
                                              int2* __restrict__ wpair,
                                              int* __restrict__ wcnt,
                                              const int* __restrict__ flag) {
  // img[784] floats (3136B) unioned with hist2[2][256] (2048B): img is dead
  // after the post-conv __syncthreads; hist writes all come after it.
  __shared__ __align__(16) unsigned char u_imghist[3136];
  __shared__ float cb[64], bcs[64];
  __shared__ __align__(16) float pooled[9216];
  __shared__ unsigned wtot[4];
  __shared__ unsigned selb, selk;
  float* img = (float*)u_imghist;
  unsigned* h2a = (unsigned*)u_imghist;           // hist2[0]
  unsigned* h2b = (unsigned*)(u_imghist + 1024);  // hist2[1]
  const int tid = threadIdx.x;
  const int b = blockIdx.x;
  const int isb = *flag;
  const int lane = tid & 63;
  const int wv_id = tid >> 6;

  for (int i = tid; i < 784; i += 256) img[i] = gload(x, b * 784 + i, isb);
  if (tid < 64) {
    cb[tid] = gload(c1b_g, tid, isb);
    float arg = (float)(400.0 / 9216.0) - gload(duty_g, tid, isb);
    bcs[tid] = (float)exp((double)arg);
  }
  __syncthreads();

  // mapping: c = tid>>2 (64), half = tid&1 (2), pg = (tid>>1)&1 (2) -> ph0 = pg*6
  {
    const int c = tid >> 2;
    const int half = tid & 1;
    const int ph0 = ((tid >> 1) & 1) * 6;
    float w[25];
#pragma unroll
    for (int i = 0; i < 25; ++i) w[i] = gload(c1w_g, c * 25 + i, isb);
    const float bias = cb[c];
    float R[6][16];
#pragma unroll
    for (int r = 0; r < 6; ++r) {
      int ir = 2 * ph0 + r;
#pragma unroll
      for (int q = 0; q < 4; ++q)
        ((float4*)&R[r][0])[q] = ((const float4*)img)[ir * 7 + half * 3 + q];
    }
#pragma unroll
    for (int i = 0; i < 6; ++i) {
      const int ph = ph0 + i;
      float a0[12], a1[12];
#pragma unroll
      for (int j = 0; j < 12; ++j) { a0[j] = 0.f; a1[j] = 0.f; }
      // single sequential fmaf chain per conv cell, k = kw*5 + kh order
      // (kh fastest -- Eigen patch linearization) => bit-exact vs reference
#pragma unroll
      for (int kj = 0; kj < 5; ++kj) {       // kw OUTER
#pragma unroll
        for (int kr = 0; kr < 5; ++kr) {     // kh INNER (fastest)
          float wk = w[kr * 5 + kj];
          const float* r0 = &R[(2 * i + kr) % 6][0];
          const float* r1 = &R[(2 * i + kr + 1) % 6][0];
#pragma unroll
          for (int j = 0; j < 12; ++j) {
            a0[j] = fmaf(r0[j + kj], wk, a0[j]);
            a1[j] = fmaf(r1[j + kj], wk, a1[j]);
          }
        }
      }
      int obase = c * 144 + ph * 12 + half * 6;
#pragma unroll
      for (int q = 0; q < 6; ++q) {
        float m = fmaxf(fmaxf(a0[2 * q], a0[2 * q + 1]),
                        fmaxf(a1[2 * q], a1[2 * q + 1]));
        pooled[obase + q] = m + bias;
      }
      if (i < 5) {  // slide: load img rows 2*ph+6, 2*ph+7 over the two oldest
        int ir0 = 2 * ph + 6, ir1 = 2 * ph + 7;
        float* d0 = &R[(2 * i) % 6][0];
        float* d1 = &R[(2 * i + 1) % 6][0];
#pragma unroll
        for (int q = 0; q < 4; ++q) {
          ((float4*)d0)[q] = ((const float4*)img)[ir0 * 7 + half * 3 + q];
          ((float4*)d1)[q] = ((const float4*)img)[ir1 * 7 + half * 3 + q];
        }
      }
    }
  }
  __syncthreads();  // after this barrier img is DEAD -> its LDS becomes hist2

  // compute this thread's 36 select keys ONCE into registers
  unsigned keys[36];
  {
    const float bcf = bcs[tid >> 2];
#pragma unroll
    for (int e4 = 0; e4 < 9; ++e4) {
      float4 pv = ((float4*)pooled)[tid * 9 + e4];
      keys[4 * e4 + 0] = tokey(pv.x * bcf);
      keys[4 * e4 + 1] = tokey(pv.y * bcf);
      keys[4 * e4 + 2] = tokey(pv.z * bcf);
      keys[4 * e4 + 3] = tokey(pv.w * bcf);
    }
  }

  // radix-select the 400th-largest key; 2 split histograms + shfl suffix scan
  unsigned kfix = 0;
  unsigned kk = 400;
  for (int pass = 3; pass >= 0; --pass) {
    const int shift = pass * 8;
    const unsigned himask = (pass == 3) ? 0u : (0xFFFFFFFFu << (shift + 8));
    h2a[tid] = 0;
    h2b[tid] = 0;
    __syncthreads();
    unsigned* myh = (wv_id < 2) ? h2a : h2b;
    if (pass == 3) {
      // run-length aggregated (all-static indices; scalars only)
      unsigned cbin = keys[0] >> 24, ccnt = 1;
#pragma unroll
      for (int e = 1; e < 36; ++e) {
        unsigned bin = keys[e] >> 24;
        if (bin == cbin) {
          ++ccnt;
        } else {
          atomicAdd(&myh[cbin], ccnt);
          cbin = bin;
          ccnt = 1;
        }
      }
      atomicAdd(&myh[cbin], ccnt);
    } else {
#pragma unroll
      for (int e = 0; e < 36; ++e) {
        unsigned key = keys[e];
        if (((key ^ kfix) & himask) == 0)
          atomicAdd(&myh[(key >> shift) & 255u], 1u);
      }
    }
    __syncthreads();
    unsigned own = h2a[tid] + h2b[tid];
    unsigned v = own;
#pragma unroll
    for (int off = 1; off < 64; off <<= 1) {
      unsigned y = __shfl_down(v, off, 64);
      if (lane + off < 64) v += y;
    }
    if (lane == 0) wtot[wv_id] = v;
    __syncthreads();
#pragma unroll
    for (int w2 = 0; w2 < 4; ++w2)
      if (w2 > wv_id) v += wtot[w2];
    unsigned snext = v - own;
    if (v >= kk && snext < kk) {
      selb = (unsigned)tid;
      selk = kk - snext;
    }
    __syncthreads();
    kfix |= selb << shift;
    kk = selk;
    // (5th barrier removed: next pass's zero->sync orders selb/selk reuse)
  }

  // sorted compaction: per-thread count -> shfl prefix scan -> ordered write.
  // keep ALL with key >= kfix (== boosted >= thr bitwise, ties kept like ref)
  unsigned mycnt = 0;
#pragma unroll
  for (int e = 0; e < 36; ++e) mycnt += (keys[e] >= kfix) ? 1u : 0u;
  unsigned px = mycnt;
#pragma unroll
  for (int off = 1; off < 64; off <<= 1) {
    unsigned y = __shfl_up(px, off, 64);
    if (lane >= off) px += y;
  }
  if (lane == 63) wtot[wv_id] = px;
  __syncthreads();
  unsigned base = 0;
#pragma unroll
  for (int w2 = 0; w2 < 4; ++w2)
    if (w2 < wv_id) base += wtot[w2];
  int pos = (int)(base + px - mycnt);  // exclusive prefix
  for (int e = 0; e < 36; ++e) {
    if (keys[e] >= kfix) {
      int o = tid * 36 + e;
      if (pos < 512)
        wpair[b * 512 + pos] = make_int2(__float_as_int(pooled[o]), o << 12);
      ++pos;
    }
  }
  if (tid == 0) {
    unsigned tot = wtot[0] + wtot[1] + wtot[2] + wtot[3];
    wcnt[b] = (int)(tot < 512u ? tot : 512u);
  }
}

// ---------------- k_fc1 v13: K-SPLIT XCD-sliced sparse fc1 gather ----------------
// r12 counters: FETCH 228MB = 6x WtF -> the 128-unit slice (9216x128x4 =
// 4.72MB) does NOT fit the 4MiB per-XCD L2; gathers thrash to HBM (~900cyc).
// v13 splits the winner-index space at o=4608: pass 0 chains winners o<4608
// (WtF rows 0..4607 -> 2.36MB/XCD slice, L2-fits), writes RAW partial acc;
// pass 1 resumes the chain from h over o>=4608 (rows 4608+, 2.36MB), adds
// bias. One sequential ascending-o fmaf chain across both passes =>
// bit-identical h. Cut found per block by redundant binary search on the
// sorted LDS wl (uniform). Keeps the r3-proven inner loop (max threads,
// 1 unit/lane, 8-pair int4 unroll).
__global__ __launch_bounds__(128) void k_fc1(const float* __restrict__ WtF,
                                             const int2* __restrict__ wpair,
                                             const int* __restrict__ wcnt,
                                             const void* __restrict__ fc1b,
                                             float* __restrict__ h,
                                             const int* __restrict__ flag,
                                             int phase) {
  __shared__ __align__(16) int2 wl[512];
  const int tid = threadIdx.x;  // 0..127
  const int img = blockIdx.x >> 3;
  const int slice = blockIdx.x & 7;
  const int isb = *flag;
  const int cnt = wcnt[img];
  const int2* __restrict__ wp = wpair + img * 512;
  for (int i = tid; i < cnt; i += 128) wl[i] = wp[i];
  __syncthreads();
  // binary search for cut = first w with o >= 4608 (p.y premult: 4608<<12)
  const int CUTY = 4608 << 12;
  int lo = 0, hi = cnt;
  while (lo < hi) {
    int mid = (lo + hi) >> 1;
    if (wl[mid].y < CUTY) lo = mid + 1; else hi = mid;
  }
  const int cut = lo;  // uniform across block
  const int u = (slice << 7) + tid;
  const char* __restrict__ Wb = (const char*)WtF + (unsigned)u * 4u;
  const int4* wl4 = (const int4*)wl;  // 2 pairs per int4, 16B-aligned
  const int wbeg = phase ? cut : 0;
  const int wend = phase ? cnt : cut;
  float acc = phase ? h[img * 1024 + u] : 0.f;
  int w = wbeg;
  if ((w & 1) && w < wend) {  // align to pair boundary for int4 reads
    int2 p = wl[w];
    acc = fmaf(__int_as_float(p.x), *(const float*)(Wb + (unsigned)p.y), acc);
    ++w;
  }
  for (; w + 8 <= wend; w += 8) {
    const int b4 = w >> 1;
    int4 q0 = wl4[b4 + 0];
    int4 q1 = wl4[b4 + 1];
    int4 q2 = wl4[b4 + 2];
    int4 q3 = wl4[b4 + 3];
    acc = fmaf(__int_as_float(q0.x), *(const float*)(Wb + (unsigned)q0.y), acc);
    acc = fmaf(__int_as_float(q0.z), *(const float*)(Wb + (unsigned)q0.w), acc);
    acc = fmaf(__int_as_float(q1.x), *(const float*)(Wb + (unsigned)q1.y), acc);
    acc = fmaf(__int_as_float(q1.z), *(const float*)(Wb + (unsigned)q1.w), acc);
    acc = fmaf(__int_as_float(q2.x), *(const float*)(Wb + (unsigned)q2.y), acc);
    acc = fmaf(__int_as_float(q2.z), *(const float*)(Wb + (unsigned)q2.w), acc);
    acc = fmaf(__int_as_float(q3.x), *(const float*)(Wb + (unsigned)q3.y), acc);
    acc = fmaf(__int_as_float(q3.z), *(const float*)(Wb + (unsigned)q3.w), acc);
  }
  for (; w < wend; ++w) {
    int2 p = wl[w];
    acc = fmaf(__int_as_float(p.x), *(const float*)(Wb + (unsigned)p.y), acc);
  }
  if (phase)
    h[img * 1024 + u] = acc + gload(fc1b, u, isb);
  else
    h[img * 1024 + u] = acc;
}

// ---------------- k_boost: fc boost factors computed ONCE ----------------
__global__ __launch_bounds__(256) void k_boost(const void* __restrict__ dutyfc,
                                               float* __restrict__ bf,
                                               const int* __restrict__ flag) {
  const int u = blockIdx.x * 256 + threadIdx.x;
  const int isb = *flag;
  if (u < 1024)
    bf[u] = (float)exp((double)(0.09765625f - gload(dutyfc, u, isb)));
}

// ---------------- k_sel v12: ONE ROW PER WAVE, zero barriers (r12-proven) ----------------
__global__ __launch_bounds__(256) void k_sel(const float* __restrict__ h,
                                             const float* __restrict__ bf,
                                             const void* __restrict__ fc2w,
                                             const void* __restrict__ fc2b,
                                             void* __restrict__ out,
                                             const int* __restrict__ flag) {
  __shared__ __align__(16) unsigned whist[4][256];
  const int tid = threadIdx.x;
  const int lane = tid & 63;
  const int wv = tid >> 6;
  const int row = blockIdx.x * 4 + wv;
  const int isb = *flag;
  unsigned* hist = whist[wv];
  volatile unsigned* vhist = whist[wv];

  // 16 units/lane, u = j*64 + lane (coalesced); keys in registers
  float hv[16];
  unsigned keys[16];
#pragma unroll
  for (int j = 0; j < 16; ++j) {
    float xv = h[row * 1024 + j * 64 + lane];
    hv[j] = xv;
    keys[j] = tokey(xv * bf[j * 64 + lane]);
  }

  // barrier-free radix select: 100th largest of the wave's 1024 keys
  unsigned kfix = 0, kk = 100;
  for (int pass = 3; pass >= 0; --pass) {
    const int shift = pass * 8;
    const unsigned himask = (pass == 3) ? 0u : (0xFFFFFFFFu << (shift + 8));
    ((uint4*)hist)[lane] = make_uint4(0u, 0u, 0u, 0u);  // 4 bins/lane zeroed
    __builtin_amdgcn_sched_barrier(0);
#pragma unroll
    for (int j = 0; j < 16; ++j) {
      if (((keys[j] ^ kfix) & himask) == 0)
        atomicAdd(&hist[(keys[j] >> shift) & 255u], 1u);
    }
    __builtin_amdgcn_sched_barrier(0);
    unsigned o0 = vhist[4 * lane + 0];
    unsigned o1 = vhist[4 * lane + 1];
    unsigned o2 = vhist[4 * lane + 2];
    unsigned o3 = vhist[4 * lane + 3];
    unsigned lsum = o0 + o1 + o2 + o3;
    unsigned v = lsum;
#pragma unroll
    for (int off = 1; off < 64; off <<= 1) {
      unsigned y = __shfl_down(v, off, 64);
      if (lane + off < 64) v += y;
    }
    const unsigned after = v - lsum;  // sum over lanes > lane
    const unsigned t3 = o3;
    const unsigned t2 = o2 + t3;
    const unsigned t1 = o1 + t2;
    const unsigned t0 = o0 + t1;
    unsigned candb = 0, candk = 0;
    bool found = false;
    const unsigned S0 = after + t0, S1 = after + t1, S2 = after + t2,
                   S3 = after + t3, S4 = after;
    if (S0 >= kk && S1 < kk) { candb = 4u * lane + 0u; candk = kk - S1; found = true; }
    else if (S1 >= kk && S2 < kk) { candb = 4u * lane + 1u; candk = kk - S2; found = true; }
    else if (S2 >= kk && S3 < kk) { candb = 4u * lane + 2u; candk = kk - S3; found = true; }
    else if (S3 >= kk && S4 < kk) { candb = 4u * lane + 3u; candk = kk - S4; found = true; }
    unsigned long long msk = __ballot(found);
    int src = __ffsll((unsigned long long)msk) - 1;  // exactly one bin matches
    candb = __shfl(candb, src, 64);
    candk = __shfl(candk, src, 64);
    kfix |= candb << shift;
    kk = candk;
  }

  // fc2 on kept units (f64), wave butterfly reduce
  double part[10];
#pragma unroll
  for (int c = 0; c < 10; ++c) part[c] = 0.0;
#pragma unroll
  for (int j = 0; j < 16; ++j) {
    if (keys[j] >= kfix) {
      const int u = j * 64 + lane;
      const double hx = (double)hv[j];
#pragma unroll
      for (int c = 0; c < 10; ++c)
        part[c] = fma(hx, (double)gload(fc2w, c * 1024 + u, isb), part[c]);
    }
  }
#pragma unroll
  for (int c = 0; c < 10; ++c) {
    double p = part[c];
#pragma unroll
    for (int off = 32; off > 0; off >>= 1) p += __shfl_xor(p, off);
    part[c] = p + (double)gload(fc2b, c, isb);
  }

  // log_softmax (f64), wave-local; static select chain for per-lane value
  double m = part[0];
#pragma unroll
  for (int c = 1; c < 10; ++c) m = part[c] > m ? part[c] : m;
  double mv = part[0];
#pragma unroll
  for (int c = 1; c < 10; ++c)
    if (lane == c) mv = part[c];
  double e = (lane < 10) ? exp(mv - m) : 0.0;  // 10 exps in parallel
  double sum = 0.0;
#pragma unroll
  for (int c = 0; c < 10; ++c) sum += __shfl(e, c, 64);  // ascending order
  double logs = log(sum);
  if (lane < 10) {
    double o = mv - m - logs;
    if (isb)
      ((unsigned short*)out)[row * 10 + lane] = f2b((float)o);
    else
      ((float*)out)[row * 10 + lane] = (float)o;
  }
}

// ---------------- launch ----------------
extern "C" void kernel_launch(void* const* d_in, const int* in_sizes, int n_in,
                              void* d_out, int out_size, void* d_ws, size_t ws_size,
                              hipStream_t stream) {
  // ws layout (bytes):
  //   WtF   : 9216*1024*4 = 37,748,736  @ 0   (reused as bf[1024] after k_fc1)
  //   wpair : 4096*512*8  = 16,777,216  @ 37,748,736
  //   wcnt  : 4096*4      =     16,384  @ 54,525,952
  //   h     : 4096*1024*4 = 16,777,216  @ 54,542,336
  //   flag  : 4                         @ 71,319,552
  char* ws = (char*)d_ws;
  float* WtF = (float*)ws;
  int2* wpair = (int2*)(ws + 37748736);
  int* wcnt = (int*)(ws + 54525952);
  float* h = (float*)(ws + 54542336);
  int* flag = (int*)(ws + 71319552);
  float* bf = WtF;  // WtF region is dead after k_fc1

  k_detect<<<1, 64, 0, stream>>>(d_in[0], flag);
  k_prep<<<dim3(144, 16), 256, 0, stream>>>(d_in[4], d_in[5], WtF, flag);
  k_conv<<<4096, 256, 0, stream>>>(d_in[0], d_in[1], d_in[2], d_in[3],
                                   wpair, wcnt, flag);
  k_fc1<<<4096 * 8, 128, 0, stream>>>(WtF, wpair, wcnt, d_in[6], h, flag, 0);
  k_fc1<<<4096 * 8, 128, 0, stream>>>(WtF, wpair, wcnt, d_in[6], h, flag, 1);
  k_boost<<<4, 256, 0, stream>>>(d_in[7], bf, flag);
  k_sel<<<1024, 256, 0, stream>>>(h, bf, d_in[8], d_in[9], d_out, flag);
}

// Round 14
// 545.465 us; speedup vs baseline: 1.0710x; 1.0191x over previous
//
#include <hip/hip_runtime.h>

// ---------------- dtype helpers ----------------
__device__ __forceinline__ float b2f(unsigned short u) {
  return __uint_as_float(((unsigned)u) << 16);
}
__device__ __forceinline__ unsigned short f2b(float f) {
  unsigned u = __float_as_uint(f);
  return (unsigned short)((u + 0x7FFFu + ((u >> 16) & 1u)) >> 16);
}
// load element i of a tensor that is bf16 (isb=1) or fp32 (isb=0)
__device__ __forceinline__ float gload(const void* p, int i, int isb) {
  return isb ? b2f(((const unsigned short*)p)[i]) : ((const float*)p)[i];
}
// monotone bijection float -> uint32 (order-preserving incl. negatives)
__device__ __forceinline__ unsigned tokey(float f) {
  unsigned u = __float_as_uint(f);
  return u ^ (unsigned)(((int)u >> 31) | 0x80000000u);
}
// local dtype derivation (replaces the k_detect kernel; identical logic ->
// identical value in every block, deterministic). Call with tid<64 only.
__device__ __forceinline__ int detect_isb_wave0(const void* x, int tid) {
  unsigned short u = ((const unsigned short*)x)[2 * tid];
  int e = (u >> 7) & 0xFF;
  unsigned long long m = __ballot(e >= 100 && e <= 140);
  return (__popcll(m) >= 40) ? 1 : 0;
}

// ---------------- k_prep: WtF[i][u] = fc1_w[u][i] * (mask<0.5), f32 transposed ----------------
__global__ __launch_bounds__(256) void k_prep(const void* __restrict__ x,
                                              const void* __restrict__ fc1w,
                                              const void* __restrict__ mraw,
                                              float* __restrict__ WtF) {
  __shared__ float tile[64][65];
  __shared__ int sflag;
  const int tid = threadIdx.x;
  if (tid < 64) {
    int f = detect_isb_wave0(x, tid);
    if (tid == 0) sflag = f;
  }
  __syncthreads();
  const int isb = sflag;
  const int i0 = blockIdx.x * 64;  // K index (9216)
  const int u0 = blockIdx.y * 64;  // unit index (1024)
  const int tx = threadIdx.x & 63, ty = threadIdx.x >> 6;
  for (int uu = ty; uu < 64; uu += 4) {
    int gi = (u0 + uu) * 9216 + i0 + tx;
    float wv = gload(fc1w, gi, isb);
    float mv = gload(mraw, gi, isb);
    tile[uu][tx] = (mv < 0.5f) ? wv : 0.0f;
  }
  __syncthreads();
  for (int ii = ty; ii < 64; ii += 4)
    WtF[(i0 + ii) * 1024 + u0 + tx] = tile[tx][ii];
}

// ---------------- k_conv: conv5x5 + pool + radix kwinners (r10-FROZEN core) ----------------
// Ladder: r3 204us -> r8 +runlength/-barrier 168 -> r9 4-block LDS 163 ->
// r10 unclamped VGPR(72, no spill) 160us @ VALUBusy 93%. Issue-saturated.
// v14 deltas (no core change): local isb derivation (k_detect killed);
// wcnt[b] packs cut = #winners with o<4608 in high 16 bits. o<4608 iff the
// winner came from waves 0/1 (tid<128: o = tid*36+e < 128*36 = 4608), so
// cut = wtot[0]+wtot[1] -- free in the existing compaction.
__global__ __launch_bounds__(256) void k_conv(const void* __restrict__ x,
                                              const void* __restrict__ c1w_g,
                                              const void* __restrict__ c1b_g,
                                              const void* __restrict__ duty_g,
                                              int2* __restrict__ wpair,
                                              int* __restrict__ wcnt) {
  // img[784] floats (3136B) unioned with hist2[2][256] (2048B): img is dead
  // after the post-conv __syncthreads; hist writes all come after it.
  __shared__ __align__(16) unsigned char u_imghist[3136];
  __shared__ float cb[64], bcs[64];
  __shared__ __align__(16) float pooled[9216];
  __shared__ unsigned wtot[4];
  __shared__ unsigned selb, selk;
  __shared__ int sflag;
  float* img = (float*)u_imghist;
  unsigned* h2a = (unsigned*)u_imghist;           // hist2[0]
  unsigned* h2b = (unsigned*)(u_imghist + 1024);  // hist2[1]
  const int tid = threadIdx.x;
  const int b = blockIdx.x;
  const int lane = tid & 63;
  const int wv_id = tid >> 6;

  if (tid < 64) {
    int f = detect_isb_wave0(x, tid);
    if (tid == 0) sflag = f;
  }
  __syncthreads();
  const int isb = sflag;

  for (int i = tid; i < 784; i += 256) img[i] = gload(x, b * 784 + i, isb);
  if (tid < 64) {
    cb[tid] = gload(c1b_g, tid, isb);
    float arg = (float)(400.0 / 9216.0) - gload(duty_g, tid, isb);
    bcs[tid] = (float)exp((double)arg);
  }
  __syncthreads();

  // mapping: c = tid>>2 (64), half = tid&1 (2), pg = (tid>>1)&1 (2) -> ph0 = pg*6
  {
    const int c = tid >> 2;
    const int half = tid & 1;
    const int ph0 = ((tid >> 1) & 1) * 6;
    float w[25];
#pragma unroll
    for (int i = 0; i < 25; ++i) w[i] = gload(c1w_g, c * 25 + i, isb);
    const float bias = cb[c];
    float R[6][16];
#pragma unroll
    for (int r = 0; r < 6; ++r) {
      int ir = 2 * ph0 + r;
#pragma unroll
      for (int q = 0; q < 4; ++q)
        ((float4*)&R[r][0])[q] = ((const float4*)img)[ir * 7 + half * 3 + q];
    }
#pragma unroll
    for (int i = 0; i < 6; ++i) {
      const int ph = ph0 + i;
      float a0[12], a1[12];
#pragma unroll
      for (int j = 0; j < 12; ++j) { a0[j] = 0.f; a1[j] = 0.f; }
      // single sequential fmaf chain per conv cell, k = kw*5 + kh order
      // (kh fastest -- Eigen patch linearization) => bit-exact vs reference
#pragma unroll
      for (int kj = 0; kj < 5; ++kj) {       // kw OUTER
#pragma unroll
        for (int kr = 0; kr < 5; ++kr) {     // kh INNER (fastest)
          float wk = w[kr * 5 + kj];
          const float* r0 = &R[(2 * i + kr) % 6][0];
          const float* r1 = &R[(2 * i + kr + 1) % 6][0];
#pragma unroll
          for (int j = 0; j < 12; ++j) {
            a0[j] = fmaf(r0[j + kj], wk, a0[j]);
            a1[j] = fmaf(r1[j + kj], wk, a1[j]);
          }
        }
      }
      int obase = c * 144 + ph * 12 + half * 6;
#pragma unroll
      for (int q = 0; q < 6; ++q) {
        float m = fmaxf(fmaxf(a0[2 * q], a0[2 * q + 1]),
                        fmaxf(a1[2 * q], a1[2 * q + 1]));
        pooled[obase + q] = m + bias;
      }
      if (i < 5) {  // slide: load img rows 2*ph+6, 2*ph+7 over the two oldest
        int ir0 = 2 * ph + 6, ir1 = 2 * ph + 7;
        float* d0 = &R[(2 * i) % 6][0];
        float* d1 = &R[(2 * i + 1) % 6][0];
#pragma unroll
        for (int q = 0; q < 4; ++q) {
          ((float4*)d0)[q] = ((const float4*)img)[ir0 * 7 + half * 3 + q];
          ((float4*)d1)[q] = ((const float4*)img)[ir1 * 7 + half * 3 + q];
        }
      }
    }
  }
  __syncthreads();  // after this barrier img is DEAD -> its LDS becomes hist2

  // compute this thread's 36 select keys ONCE into registers
  unsigned keys[36];
  {
    const float bcf = bcs[tid >> 2];
#pragma unroll
    for (int e4 = 0; e4 < 9; ++e4) {
      float4 pv = ((float4*)pooled)[tid * 9 + e4];
      keys[4 * e4 + 0] = tokey(pv.x * bcf);
      keys[4 * e4 + 1] = tokey(pv.y * bcf);
      keys[4 * e4 + 2] = tokey(pv.z * bcf);
      keys[4 * e4 + 3] = tokey(pv.w * bcf);
    }
  }

  // radix-select the 400th-largest key; 2 split histograms + shfl suffix scan
  unsigned kfix = 0;
  unsigned kk = 400;
  for (int pass = 3; pass >= 0; --pass) {
    const int shift = pass * 8;
    const unsigned himask = (pass == 3) ? 0u : (0xFFFFFFFFu << (shift + 8));
    h2a[tid] = 0;
    h2b[tid] = 0;
    __syncthreads();
    unsigned* myh = (wv_id < 2) ? h2a : h2b;
    if (pass == 3) {
      // run-length aggregated (all-static indices; scalars only)
      unsigned cbin = keys[0] >> 24, ccnt = 1;
#pragma unroll
      for (int e = 1; e < 36; ++e) {
        unsigned bin = keys[e] >> 24;
        if (bin == cbin) {
          ++ccnt;
        } else {
          atomicAdd(&myh[cbin], ccnt);
          cbin = bin;
          ccnt = 1;
        }
      }
      atomicAdd(&myh[cbin], ccnt);
    } else {
#pragma unroll
      for (int e = 0; e < 36; ++e) {
        unsigned key = keys[e];
        if (((key ^ kfix) & himask) == 0)
          atomicAdd(&myh[(key >> shift) & 255u], 1u);
      }
    }
    __syncthreads();
    unsigned own = h2a[tid] + h2b[tid];
    unsigned v = own;
#pragma unroll
    for (int off = 1; off < 64; off <<= 1) {
      unsigned y = __shfl_down(v, off, 64);
      if (lane + off < 64) v += y;
    }
    if (lane == 0) wtot[wv_id] = v;
    __syncthreads();
#pragma unroll
    for (int w2 = 0; w2 < 4; ++w2)
      if (w2 > wv_id) v += wtot[w2];
    unsigned snext = v - own;
    if (v >= kk && snext < kk) {
      selb = (unsigned)tid;
      selk = kk - snext;
    }
    __syncthreads();
    kfix |= selb << shift;
    kk = selk;
    // (5th barrier removed: next pass's zero->sync orders selb/selk reuse)
  }

  // sorted compaction: per-thread count -> shfl prefix scan -> ordered write.
  // keep ALL with key >= kfix (== boosted >= thr bitwise, ties kept like ref)
  unsigned mycnt = 0;
#pragma unroll
  for (int e = 0; e < 36; ++e) mycnt += (keys[e] >= kfix) ? 1u : 0u;
  unsigned px = mycnt;
#pragma unroll
  for (int off = 1; off < 64; off <<= 1) {
    unsigned y = __shfl_up(px, off, 64);
    if (lane >= off) px += y;
  }
  if (lane == 63) wtot[wv_id] = px;
  __syncthreads();
  unsigned base = 0;
#pragma unroll
  for (int w2 = 0; w2 < 4; ++w2)
    if (w2 < wv_id) base += wtot[w2];
  int pos = (int)(base + px - mycnt);  // exclusive prefix
  for (int e = 0; e < 36; ++e) {
    if (keys[e] >= kfix) {
      int o = tid * 36 + e;
      if (pos < 512)
        wpair[b * 512 + pos] = make_int2(__float_as_int(pooled[o]), o << 12);
      ++pos;
    }
  }
  if (tid == 0) {
    unsigned tot = wtot[0] + wtot[1] + wtot[2] + wtot[3];
    unsigned cut = wtot[0] + wtot[1];  // winners with o < 4608
    if (tot > 512u) tot = 512u;
    if (cut > 512u) cut = 512u;
    wcnt[b] = (int)(tot | (cut << 16));
  }
}

// ---------------- k_fc1 v14: K-SPLIT gather, half-range staging ----------------
// r13 delta-arithmetic: fc1 = 2x134us at ~26 TB/s effective L2 read -- at the
// practical L2 BW ceiling; 7.05 GB gather traffic is algorithmically minimal.
// v14 trims the non-gather overhead: cut comes precomputed in wcnt's high
// bits (no binary search), and each pass stages ONLY its half-range of the
// winner list (halves wpair staging traffic). Chain order: one sequential
// ascending-o fmaf chain across the two passes => bit-identical h.
__global__ __launch_bounds__(128) void k_fc1(const float* __restrict__ WtF,
                                             const int2* __restrict__ wpair,
                                             const int* __restrict__ wcnt,
                                             const void* __restrict__ fc1b,
                                             float* __restrict__ h,
                                             const void* __restrict__ x,
                                             int phase) {
  __shared__ __align__(16) int2 wl[512];
  __shared__ int sflag;
  const int tid = threadIdx.x;  // 0..127
  const int img = blockIdx.x >> 3;
  const int slice = blockIdx.x & 7;
  if (tid < 64) {
    int f = detect_isb_wave0(x, tid);
    if (tid == 0) sflag = f;
  }
  const unsigned wc = (unsigned)wcnt[img];
  const int cnt = (int)(wc & 0xFFFFu);
  const int cut = (int)(wc >> 16);
  const int beg = phase ? cut : 0;
  const int len = (phase ? cnt : cut) - beg;
  const int2* __restrict__ wp = wpair + img * 512 + beg;
  for (int i = tid; i < len; i += 128) wl[i] = wp[i];
  __syncthreads();
  const int isb = sflag;
  const int u = (slice << 7) + tid;
  const char* __restrict__ Wb = (const char*)WtF + (unsigned)u * 4u;
  const int4* wl4 = (const int4*)wl;  // 2 pairs per int4, 16B-aligned
  float acc = phase ? h[img * 1024 + u] : 0.f;
  int w = 0;
  for (; w + 8 <= len; w += 8) {
    const int b4 = w >> 1;
    int4 q0 = wl4[b4 + 0];
    int4 q1 = wl4[b4 + 1];
    int4 q2 = wl4[b4 + 2];
    int4 q3 = wl4[b4 + 3];
    acc = fmaf(__int_as_float(q0.x), *(const float*)(Wb + (unsigned)q0.y), acc);
    acc = fmaf(__int_as_float(q0.z), *(const float*)(Wb + (unsigned)q0.w), acc);
    acc = fmaf(__int_as_float(q1.x), *(const float*)(Wb + (unsigned)q1.y), acc);
    acc = fmaf(__int_as_float(q1.z), *(const float*)(Wb + (unsigned)q1.w), acc);
    acc = fmaf(__int_as_float(q2.x), *(const float*)(Wb + (unsigned)q2.y), acc);
    acc = fmaf(__int_as_float(q2.z), *(const float*)(Wb + (unsigned)q2.w), acc);
    acc = fmaf(__int_as_float(q3.x), *(const float*)(Wb + (unsigned)q3.y), acc);
    acc = fmaf(__int_as_float(q3.z), *(const float*)(Wb + (unsigned)q3.w), acc);
  }
  for (; w < len; ++w) {
    int2 p = wl[w];
    acc = fmaf(__int_as_float(p.x), *(const float*)(Wb + (unsigned)p.y), acc);
  }
  if (phase)
    h[img * 1024 + u] = acc + gload(fc1b, u, isb);
  else
    h[img * 1024 + u] = acc;
}

// ---------------- k_sel v14: row-per-wave + in-block bf table (k_boost killed) ----------------
// r12-proven barrier-free radix select; v14 computes the 1024-entry boost
// table into LDS per block (4 f64 exps/thread, identical expression =>
// bit-identical values) -- removes the k_boost launch and the bf-in-WtF
// aliasing.
__global__ __launch_bounds__(256) void k_sel(const float* __restrict__ h,
                                             const void* __restrict__ dutyfc,
                                             const void* __restrict__ fc2w,
                                             const void* __restrict__ fc2b,
                                             void* __restrict__ out,
                                             const void* __restrict__ x) {
  __shared__ __align__(16) unsigned whist[4][256];
  __shared__ __align__(16) float bfl[1024];
  __shared__ int sflag;
  const int tid = threadIdx.x;
  const int lane = tid & 63;
  const int wv = tid >> 6;
  const int row = blockIdx.x * 4 + wv;
  if (tid < 64) {
    int f = detect_isb_wave0(x, tid);
    if (tid == 0) sflag = f;
  }
  __syncthreads();
  const int isb = sflag;
  for (int i = tid; i < 1024; i += 256)
    bfl[i] = (float)exp((double)(0.09765625f - gload(dutyfc, i, isb)));
  __syncthreads();
  unsigned* hist = whist[wv];
  volatile unsigned* vhist = whist[wv];

  // 16 units/lane, u = j*64 + lane (coalesced); keys in registers
  float hv[16];
  unsigned keys[16];
#pragma unroll
  for (int j = 0; j < 16; ++j) {
    float xv = h[row * 1024 + j * 64 + lane];
    hv[j] = xv;
    keys[j] = tokey(xv * bfl[j * 64 + lane]);
  }

  // barrier-free radix select: 100th largest of the wave's 1024 keys
  unsigned kfix = 0, kk = 100;
  for (int pass = 3; pass >= 0; --pass) {
    const int shift = pass * 8;
    const unsigned himask = (pass == 3) ? 0u : (0xFFFFFFFFu << (shift + 8));
    ((uint4*)hist)[lane] = make_uint4(0u, 0u, 0u, 0u);  // 4 bins/lane zeroed
    __builtin_amdgcn_sched_barrier(0);
#pragma unroll
    for (int j = 0; j < 16; ++j) {
      if (((keys[j] ^ kfix) & himask) == 0)
        atomicAdd(&hist[(keys[j] >> shift) & 255u], 1u);
    }
    __builtin_amdgcn_sched_barrier(0);
    unsigned o0 = vhist[4 * lane + 0];
    unsigned o1 = vhist[4 * lane + 1];
    unsigned o2 = vhist[4 * lane + 2];
    unsigned o3 = vhist[4 * lane + 3];
    unsigned lsum = o0 + o1 + o2 + o3;
    unsigned v = lsum;
#pragma unroll
    for (int off = 1; off < 64; off <<= 1) {
      unsigned y = __shfl_down(v, off, 64);
      if (lane + off < 64) v += y;
    }
    const unsigned after = v - lsum;  // sum over lanes > lane
    const unsigned t3 = o3;
    const unsigned t2 = o2 + t3;
    const unsigned t1 = o1 + t2;
    const unsigned t0 = o0 + t1;
    unsigned candb = 0, candk = 0;
    bool found = false;
    const unsigned S0 = after + t0, S1 = after + t1, S2 = after + t2,
                   S3 = after + t3, S4 = after;
    if (S0 >= kk && S1 < kk) { candb = 4u * lane + 0u; candk = kk - S1; found = true; }
    else if (S1 >= kk && S2 < kk) { candb = 4u * lane + 1u; candk = kk - S2; found = true; }
    else if (S2 >= kk && S3 < kk) { candb = 4u * lane + 2u; candk = kk - S3; found = true; }
    else if (S3 >= kk && S4 < kk) { candb = 4u * lane + 3u; candk = kk - S4; found = true; }
    unsigned long long msk = __ballot(found);
    int src = __ffsll((unsigned long long)msk) - 1;  // exactly one bin matches
    candb = __shfl(candb, src, 64);
    candk = __shfl(candk, src, 64);
    kfix |= candb << shift;
    kk = candk;
  }

  // fc2 on kept units (f64), wave butterfly reduce
  double part[10];
#pragma unroll
  for (int c = 0; c < 10; ++c) part[c] = 0.0;
#pragma unroll
  for (int j = 0; j < 16; ++j) {
    if (keys[j] >= kfix) {
      const int u = j * 64 + lane;
      const double hx = (double)hv[j];
#pragma unroll
      for (int c = 0; c < 10; ++c)
        part[c] = fma(hx, (double)gload(fc2w, c * 1024 + u, isb), part[c]);
    }
  }
#pragma unroll
  for (int c = 0; c < 10; ++c) {
    double p = part[c];
#pragma unroll
    for (int off = 32; off > 0; off >>= 1) p += __shfl_xor(p, off);
    part[c] = p + (double)gload(fc2b, c, isb);
  }

  // log_softmax (f64), wave-local; static select chain for per-lane value
  double m = part[0];
#pragma unroll
  for (int c = 1; c < 10; ++c) m = part[c] > m ? part[c] : m;
  double mv = part[0];
#pragma unroll
  for (int c = 1; c < 10; ++c)
    if (lane == c) mv = part[c];
  double e = (lane < 10) ? exp(mv - m) : 0.0;  // 10 exps in parallel
  double sum = 0.0;
#pragma unroll
  for (int c = 0; c < 10; ++c) sum += __shfl(e, c, 64);  // ascending order
  double logs = log(sum);
  if (lane < 10) {
    double o = mv - m - logs;
    if (isb)
      ((unsigned short*)out)[row * 10 + lane] = f2b((float)o);
    else
      ((float*)out)[row * 10 + lane] = (float)o;
  }
}

// ---------------- launch ----------------
extern "C" void kernel_launch(void* const* d_in, const int* in_sizes, int n_in,
                              void* d_out, int out_size, void* d_ws, size_t ws_size,
                              hipStream_t stream) {
  // ws layout (bytes):
  //   WtF   : 9216*1024*4 = 37,748,736  @ 0
  //   wpair : 4096*512*8  = 16,777,216  @ 37,748,736
  //   wcnt  : 4096*4      =     16,384  @ 54,525,952   (lo16 = cnt, hi16 = cut)
  //   h     : 4096*1024*4 = 16,777,216  @ 54,542,336
  char* ws = (char*)d_ws;
  float* WtF = (float*)ws;
  int2* wpair = (int2*)(ws + 37748736);
  int* wcnt = (int*)(ws + 54525952);
  float* h = (float*)(ws + 54542336);

  k_prep<<<dim3(144, 16), 256, 0, stream>>>(d_in[0], d_in[4], d_in[5], WtF);
  k_conv<<<4096, 256, 0, stream>>>(d_in[0], d_in[1], d_in[2], d_in[3],
                                   wpair, wcnt);
  k_fc1<<<4096 * 8, 128, 0, stream>>>(WtF, wpair, wcnt, d_in[6], h, d_in[0], 0);
  k_fc1<<<4096 * 8, 128, 0, stream>>>(WtF, wpair, wcnt, d_in[6], h, d_in[0], 1);
  k_sel<<<1024, 256, 0, stream>>>(h, d_in[7], d_in[8], d_in[9], d_out, d_in[0]);
}

// Round 15
// 540.340 us; speedup vs baseline: 1.0811x; 1.0095x over previous
//
#include <hip/hip_runtime.h>

// ---------------- dtype helpers ----------------
__device__ __forceinline__ float b2f(unsigned short u) {
  return __uint_as_float(((unsigned)u) << 16);
}
__device__ __forceinline__ unsigned short f2b(float f) {
  unsigned u = __float_as_uint(f);
  return (unsigned short)((u + 0x7FFFu + ((u >> 16) & 1u)) >> 16);
}
// load element i of a tensor that is bf16 (isb=1) or fp32 (isb=0)
__device__ __forceinline__ float gload(const void* p, int i, int isb) {
  return isb ? b2f(((const unsigned short*)p)[i]) : ((const float*)p)[i];
}
// monotone bijection float -> uint32 (order-preserving incl. negatives)
__device__ __forceinline__ unsigned tokey(float f) {
  unsigned u = __float_as_uint(f);
  return u ^ (unsigned)(((int)u >> 31) | 0x80000000u);
}

// ---------------- dtype detector kernel (RESTORED from r13) ----------------
// r14 post-mortem: deriving isb in-kernel (ballot+LDS+barrier) gated every
// isb-dependent gload behind a barrier round-trip -> defeated load hoisting,
// k_conv +49us stall at identical busy-cycles. A single early s_load of
// *flag is the proven-fast form.
__global__ void k_detect(const void* x, int* flag) {
  int tid = threadIdx.x;  // 1 wave
  unsigned short u = ((const unsigned short*)x)[2 * tid];
  int e = (u >> 7) & 0xFF;
  bool sane = (e >= 100 && e <= 140);
  unsigned long long m = __ballot(sane);
  if (tid == 0) *flag = (__popcll(m) >= 40) ? 1 : 0;
}

// ---------------- k_prep: WtF[i][u] = fc1_w[u][i] * (mask<0.5), f32 transposed ----------------
__global__ __launch_bounds__(256) void k_prep(const void* __restrict__ fc1w,
                                              const void* __restrict__ mraw,
                                              float* __restrict__ WtF,
                                              const int* __restrict__ flag) {
  __shared__ float tile[64][65];
  const int isb = *flag;
  const int i0 = blockIdx.x * 64;  // K index (9216)
  const int u0 = blockIdx.y * 64;  // unit index (1024)
  const int tx = threadIdx.x & 63, ty = threadIdx.x >> 6;
  for (int uu = ty; uu < 64; uu += 4) {
    int gi = (u0 + uu) * 9216 + i0 + tx;
    float wv = gload(fc1w, gi, isb);
    float mv = gload(mraw, gi, isb);
    tile[uu][tx] = (mv < 0.5f) ? wv : 0.0f;
  }
  __syncthreads();
  for (int ii = ty; ii < 64; ii += 4)
    WtF[(i0 + ii) * 1024 + u0 + tx] = tile[tx][ii];
}

// ---------------- k_conv: conv5x5 + pool + radix kwinners (r10-FROZEN core, *flag isb) ----------------
// Ladder: r3 204us -> r8 +runlength/-barrier 168 -> r9 4-block LDS 163 ->
// r10 unclamped VGPR(72, no spill) 160us @ VALUBusy 93%. Issue-saturated.
// Keeps r14's wcnt packing: hi16 = cut = #winners with o<4608 (= waves 0/1,
// since o = tid*36+e < 128*36 = 4608) -- 3 SALU ops at kernel end.
__global__ __launch_bounds__(256) void k_conv(const void* __restrict__ x,
                                              const void* __restrict__ c1w_g,
                                              const void* __restrict__ c1b_g,
                                              const void* __restrict__ duty_g,
                                              int2* __restrict__ wpair,
                                              int* __restrict__ wcnt,
                                              const int* __restrict__ flag) {
  // img[784] floats (3136B) unioned with hist2[2][256] (2048B): img is dead
  // after the post-conv __syncthreads; hist writes all come after it.
  __shared__ __align__(16) unsigned char u_imghist[3136];
  __shared__ float cb[64], bcs[64];
  __shared__ __align__(16) float pooled[9216];
  __shared__ unsigned wtot[4];
  __shared__ unsigned selb, selk;
  float* img = (float*)u_imghist;
  unsigned* h2a = (unsigned*)u_imghist;           // hist2[0]
  unsigned* h2b = (unsigned*)(u_imghist + 1024);  // hist2[1]
  const int tid = threadIdx.x;
  const int b = blockIdx.x;
  const int isb = *flag;
  const int lane = tid & 63;
  const int wv_id = tid >> 6;

  for (int i = tid; i < 784; i += 256) img[i] = gload(x, b * 784 + i, isb);
  if (tid < 64) {
    cb[tid] = gload(c1b_g, tid, isb);
    float arg = (float)(400.0 / 9216.0) - gload(duty_g, tid, isb);
    bcs[tid] = (float)exp((double)arg);
  }
  __syncthreads();

  // mapping: c = tid>>2 (64), half = tid&1 (2), pg = (tid>>1)&1 (2) -> ph0 = pg*6
  {
    const int c = tid >> 2;
    const int half = tid & 1;
    const int ph0 = ((tid >> 1) & 1) * 6;
    float w[25];
#pragma unroll
    for (int i = 0; i < 25; ++i) w[i] = gload(c1w_g, c * 25 + i, isb);
    const float bias = cb[c];
    float R[6][16];
#pragma unroll
    for (int r = 0; r < 6; ++r) {
      int ir = 2 * ph0 + r;
#pragma unroll
      for (int q = 0; q < 4; ++q)
        ((float4*)&R[r][0])[q] = ((const float4*)img)[ir * 7 + half * 3 + q];
    }
#pragma unroll
    for (int i = 0; i < 6; ++i) {
      const int ph = ph0 + i;
      float a0[12], a1[12];
#pragma unroll
      for (int j = 0; j < 12; ++j) { a0[j] = 0.f; a1[j] = 0.f; }
      // single sequential fmaf chain per conv cell, k = kw*5 + kh order
      // (kh fastest -- Eigen patch linearization) => bit-exact vs reference
#pragma unroll
      for (int kj = 0; kj < 5; ++kj) {       // kw OUTER
#pragma unroll
        for (int kr = 0; kr < 5; ++kr) {     // kh INNER (fastest)
          float wk = w[kr * 5 + kj];
          const float* r0 = &R[(2 * i + kr) % 6][0];
          const float* r1 = &R[(2 * i + kr + 1) % 6][0];
#pragma unroll
          for (int j = 0; j < 12; ++j) {
            a0[j] = fmaf(r0[j + kj], wk, a0[j]);
            a1[j] = fmaf(r1[j + kj], wk, a1[j]);
          }
        }
      }
      int obase = c * 144 + ph * 12 + half * 6;
#pragma unroll
      for (int q = 0; q < 6; ++q) {
        float m = fmaxf(fmaxf(a0[2 * q], a0[2 * q + 1]),
                        fmaxf(a1[2 * q], a1[2 * q + 1]));
        pooled[obase + q] = m + bias;
      }
      if (i < 5) {  // slide: load img rows 2*ph+6, 2*ph+7 over the two oldest
        int ir0 = 2 * ph + 6, ir1 = 2 * ph + 7;
        float* d0 = &R[(2 * i) % 6][0];
        float* d1 = &R[(2 * i + 1) % 6][0];
#pragma unroll
        for (int q = 0; q < 4; ++q) {
          ((float4*)d0)[q] = ((const float4*)img)[ir0 * 7 + half * 3 + q];
          ((float4*)d1)[q] = ((const float4*)img)[ir1 * 7 + half * 3 + q];
        }
      }
    }
  }
  __syncthreads();  // after this barrier img is DEAD -> its LDS becomes hist2

  // compute this thread's 36 select keys ONCE into registers
  unsigned keys[36];
  {
    const float bcf = bcs[tid >> 2];
#pragma unroll
    for (int e4 = 0; e4 < 9; ++e4) {
      float4 pv = ((float4*)pooled)[tid * 9 + e4];
      keys[4 * e4 + 0] = tokey(pv.x * bcf);
      keys[4 * e4 + 1] = tokey(pv.y * bcf);
      keys[4 * e4 + 2] = tokey(pv.z * bcf);
      keys[4 * e4 + 3] = tokey(pv.w * bcf);
    }
  }

  // radix-select the 400th-largest key; 2 split histograms + shfl suffix scan
  unsigned kfix = 0;
  unsigned kk = 400;
  for (int pass = 3; pass >= 0; --pass) {
    const int shift = pass * 8;
    const unsigned himask = (pass == 3) ? 0u : (0xFFFFFFFFu << (shift + 8));
    h2a[tid] = 0;
    h2b[tid] = 0;
    __syncthreads();
    unsigned* myh = (wv_id < 2) ? h2a : h2b;
    if (pass == 3) {
      // run-length aggregated (all-static indices; scalars only)
      unsigned cbin = keys[0] >> 24, ccnt = 1;
#pragma unroll
      for (int e = 1; e < 36; ++e) {
        unsigned bin = keys[e] >> 24;
        if (bin == cbin) {
          ++ccnt;
        } else {
          atomicAdd(&myh[cbin], ccnt);
          cbin = bin;
          ccnt = 1;
        }
      }
      atomicAdd(&myh[cbin], ccnt);
    } else {
#pragma unroll
      for (int e = 0; e < 36; ++e) {
        unsigned key = keys[e];
        if (((key ^ kfix) & himask) == 0)
          atomicAdd(&myh[(key >> shift) & 255u], 1u);
      }
    }
    __syncthreads();
    unsigned own = h2a[tid] + h2b[tid];
    unsigned v = own;
#pragma unroll
    for (int off = 1; off < 64; off <<= 1) {
      unsigned y = __shfl_down(v, off, 64);
      if (lane + off < 64) v += y;
    }
    if (lane == 0) wtot[wv_id] = v;
    __syncthreads();
#pragma unroll
    for (int w2 = 0; w2 < 4; ++w2)
      if (w2 > wv_id) v += wtot[w2];
    unsigned snext = v - own;
    if (v >= kk && snext < kk) {
      selb = (unsigned)tid;
      selk = kk - snext;
    }
    __syncthreads();
    kfix |= selb << shift;
    kk = selk;
    // (5th barrier removed: next pass's zero->sync orders selb/selk reuse)
  }

  // sorted compaction: per-thread count -> shfl prefix scan -> ordered write.
  // keep ALL with key >= kfix (== boosted >= thr bitwise, ties kept like ref)
  unsigned mycnt = 0;
#pragma unroll
  for (int e = 0; e < 36; ++e) mycnt += (keys[e] >= kfix) ? 1u : 0u;
  unsigned px = mycnt;
#pragma unroll
  for (int off = 1; off < 64; off <<= 1) {
    unsigned y = __shfl_up(px, off, 64);
    if (lane >= off) px += y;
  }
  if (lane == 63) wtot[wv_id] = px;
  __syncthreads();
  unsigned base = 0;
#pragma unroll
  for (int w2 = 0; w2 < 4; ++w2)
    if (w2 < wv_id) base += wtot[w2];
  int pos = (int)(base + px - mycnt);  // exclusive prefix
  for (int e = 0; e < 36; ++e) {
    if (keys[e] >= kfix) {
      int o = tid * 36 + e;
      if (pos < 512)
        wpair[b * 512 + pos] = make_int2(__float_as_int(pooled[o]), o << 12);
      ++pos;
    }
  }
  if (tid == 0) {
    unsigned tot = wtot[0] + wtot[1] + wtot[2] + wtot[3];
    unsigned cut = wtot[0] + wtot[1];  // winners with o < 4608
    if (tot > 512u) tot = 512u;
    if (cut > 512u) cut = 512u;
    wcnt[b] = (int)(tot | (cut << 16));
  }
}

// ---------------- k_fc1: K-SPLIT gather, half-range staging (*flag isb) ----------------
// r13 delta-arithmetic: fc1 = 2 passes at ~26 TB/s effective L2 read -- at
// the practical L2 BW ceiling; 7.05 GB gather traffic is algorithmically
// minimal. Half-range staging from packed wcnt (no binary search). Chain:
// one sequential ascending-o fmaf chain across the two passes => bit-exact.
__global__ __launch_bounds__(128) void k_fc1(const float* __restrict__ WtF,
                                             const int2* __restrict__ wpair,
                                             const int* __restrict__ wcnt,
                                             const void* __restrict__ fc1b,
                                             float* __restrict__ h,
                                             const int* __restrict__ flag,
                                             int phase) {
  __shared__ __align__(16) int2 wl[512];
  const int tid = threadIdx.x;  // 0..127
  const int img = blockIdx.x >> 3;
  const int slice = blockIdx.x & 7;
  const int isb = *flag;
  const unsigned wc = (unsigned)wcnt[img];
  const int cnt = (int)(wc & 0xFFFFu);
  const int cut = (int)(wc >> 16);
  const int beg = phase ? cut : 0;
  const int len = (phase ? cnt : cut) - beg;
  const int2* __restrict__ wp = wpair + img * 512 + beg;
  for (int i = tid; i < len; i += 128) wl[i] = wp[i];
  __syncthreads();
  const int u = (slice << 7) + tid;
  const char* __restrict__ Wb = (const char*)WtF + (unsigned)u * 4u;
  const int4* wl4 = (const int4*)wl;  // 2 pairs per int4, 16B-aligned
  float acc = phase ? h[img * 1024 + u] : 0.f;
  int w = 0;
  for (; w + 8 <= len; w += 8) {
    const int b4 = w >> 1;
    int4 q0 = wl4[b4 + 0];
    int4 q1 = wl4[b4 + 1];
    int4 q2 = wl4[b4 + 2];
    int4 q3 = wl4[b4 + 3];
    acc = fmaf(__int_as_float(q0.x), *(const float*)(Wb + (unsigned)q0.y), acc);
    acc = fmaf(__int_as_float(q0.z), *(const float*)(Wb + (unsigned)q0.w), acc);
    acc = fmaf(__int_as_float(q1.x), *(const float*)(Wb + (unsigned)q1.y), acc);
    acc = fmaf(__int_as_float(q1.z), *(const float*)(Wb + (unsigned)q1.w), acc);
    acc = fmaf(__int_as_float(q2.x), *(const float*)(Wb + (unsigned)q2.y), acc);
    acc = fmaf(__int_as_float(q2.z), *(const float*)(Wb + (unsigned)q2.w), acc);
    acc = fmaf(__int_as_float(q3.x), *(const float*)(Wb + (unsigned)q3.y), acc);
    acc = fmaf(__int_as_float(q3.z), *(const float*)(Wb + (unsigned)q3.w), acc);
  }
  for (; w < len; ++w) {
    int2 p = wl[w];
    acc = fmaf(__int_as_float(p.x), *(const float*)(Wb + (unsigned)p.y), acc);
  }
  if (phase)
    h[img * 1024 + u] = acc + gload(fc1b, u, isb);
  else
    h[img * 1024 + u] = acc;
}

// ---------------- k_sel: row-per-wave barrier-free select + in-block bf table ----------------
// r12-proven barrier-free radix select; bf table computed into LDS per block
// (identical f64 expression => bit-identical). isb via early *flag s_load.
__global__ __launch_bounds__(256) void k_sel(const float* __restrict__ h,
                                             const void* __restrict__ dutyfc,
                                             const void* __restrict__ fc2w,
                                             const void* __restrict__ fc2b,
                                             void* __restrict__ out,
                                             const int* __restrict__ flag) {
  __shared__ __align__(16) unsigned whist[4][256];
  __shared__ __align__(16) float bfl[1024];
  const int tid = threadIdx.x;
  const int lane = tid & 63;
  const int wv = tid >> 6;
  const int row = blockIdx.x * 4 + wv;
  const int isb = *flag;
  for (int i = tid; i < 1024; i += 256)
    bfl[i] = (float)exp((double)(0.09765625f - gload(dutyfc, i, isb)));
  __syncthreads();
  unsigned* hist = whist[wv];
  volatile unsigned* vhist = whist[wv];

  // 16 units/lane, u = j*64 + lane (coalesced); keys in registers
  float hv[16];
  unsigned keys[16];
#pragma unroll
  for (int j = 0; j < 16; ++j) {
    float xv = h[row * 1024 + j * 64 + lane];
    hv[j] = xv;
    keys[j] = tokey(xv * bfl[j * 64 + lane]);
  }

  // barrier-free radix select: 100th largest of the wave's 1024 keys
  unsigned kfix = 0, kk = 100;
  for (int pass = 3; pass >= 0; --pass) {
    const int shift = pass * 8;
    const unsigned himask = (pass == 3) ? 0u : (0xFFFFFFFFu << (shift + 8));
    ((uint4*)hist)[lane] = make_uint4(0u, 0u, 0u, 0u);  // 4 bins/lane zeroed
    __builtin_amdgcn_sched_barrier(0);
#pragma unroll
    for (int j = 0; j < 16; ++j) {
      if (((keys[j] ^ kfix) & himask) == 0)
        atomicAdd(&hist[(keys[j] >> shift) & 255u], 1u);
    }
    __builtin_amdgcn_sched_barrier(0);
    unsigned o0 = vhist[4 * lane + 0];
    unsigned o1 = vhist[4 * lane + 1];
    unsigned o2 = vhist[4 * lane + 2];
    unsigned o3 = vhist[4 * lane + 3];
    unsigned lsum = o0 + o1 + o2 + o3;
    unsigned v = lsum;
#pragma unroll
    for (int off = 1; off < 64; off <<= 1) {
      unsigned y = __shfl_down(v, off, 64);
      if (lane + off < 64) v += y;
    }
    const unsigned after = v - lsum;  // sum over lanes > lane
    const unsigned t3 = o3;
    const unsigned t2 = o2 + t3;
    const unsigned t1 = o1 + t2;
    const unsigned t0 = o0 + t1;
    unsigned candb = 0, candk = 0;
    bool found = false;
    const unsigned S0 = after + t0, S1 = after + t1, S2 = after + t2,
                   S3 = after + t3, S4 = after;
    if (S0 >= kk && S1 < kk) { candb = 4u * lane + 0u; candk = kk - S1; found = true; }
    else if (S1 >= kk && S2 < kk) { candb = 4u * lane + 1u; candk = kk - S2; found = true; }
    else if (S2 >= kk && S3 < kk) { candb = 4u * lane + 2u; candk = kk - S3; found = true; }
    else if (S3 >= kk && S4 < kk) { candb = 4u * lane + 3u; candk = kk - S4; found = true; }
    unsigned long long msk = __ballot(found);
    int src = __ffsll((unsigned long long)msk) - 1;  // exactly one bin matches
    candb = __shfl(candb, src, 64);
    candk = __shfl(candk, src, 64);
    kfix |= candb << shift;
    kk = candk;
  }

  // fc2 on kept units (f64), wave butterfly reduce
  double part[10];
#pragma unroll
  for (int c = 0; c < 10; ++c) part[c] = 0.0;
#pragma unroll
  for (int j = 0; j < 16; ++j) {
    if (keys[j] >= kfix) {
      const int u = j * 64 + lane;
      const double hx = (double)hv[j];
#pragma unroll
      for (int c = 0; c < 10; ++c)
        part[c] = fma(hx, (double)gload(fc2w, c * 1024 + u, isb), part[c]);
    }
  }
#pragma unroll
  for (int c = 0; c < 10; ++c) {
    double p = part[c];
#pragma unroll
    for (int off = 32; off > 0; off >>= 1) p += __shfl_xor(p, off);
    part[c] = p + (double)gload(fc2b, c, isb);
  }

  // log_softmax (f64), wave-local; static select chain for per-lane value
  double m = part[0];
#pragma unroll
  for (int c = 1; c < 10; ++c) m = part[c] > m ? part[c] : m;
  double mv = part[0];
#pragma unroll
  for (int c = 1; c < 10; ++c)
    if (lane == c) mv = part[c];
  double e = (lane < 10) ? exp(mv - m) : 0.0;  // 10 exps in parallel
  double sum = 0.0;
#pragma unroll
  for (int c = 0; c < 10; ++c) sum += __shfl(e, c, 64);  // ascending order
  double logs = log(sum);
  if (lane < 10) {
    double o = mv - m - logs;
    if (isb)
      ((unsigned short*)out)[row * 10 + lane] = f2b((float)o);
    else
      ((float*)out)[row * 10 + lane] = (float)o;
  }
}

// ---------------- launch ----------------
extern "C" void kernel_launch(void* const* d_in, const int* in_sizes, int n_in,
                              void* d_out, int out_size, void* d_ws, size_t ws_size,
                              hipStream_t stream) {
  // ws layout (bytes):
  //   WtF   : 9216*1024*4 = 37,748,736  @ 0
  //   wpair : 4096*512*8  = 16,777,216  @ 37,748,736
  //   wcnt  : 4096*4      =     16,384  @ 54,525,952   (lo16 = cnt, hi16 = cut)
  //   h     : 4096*1024*4 = 16,777,216  @ 54,542,336
  //   flag  : 4                         @ 71,319,552
  char* ws = (char*)d_ws;
  float* WtF = (float*)ws;
  int2* wpair = (int2*)(ws + 37748736);
  int* wcnt = (int*)(ws + 54525952);
  float* h = (float*)(ws + 54542336);
  int* flag = (int*)(ws + 71319552);

  k_detect<<<1, 64, 0, stream>>>(d_in[0], flag);
  k_prep<<<dim3(144, 16), 256, 0, stream>>>(d_in[4], d_in[5], WtF, flag);
  k_conv<<<4096, 256, 0, stream>>>(d_in[0], d_in[1], d_in[2], d_in[3],
                                   wpair, wcnt, flag);
  k_fc1<<<4096 * 8, 128, 0, stream>>>(WtF, wpair, wcnt, d_in[6], h, flag, 0);
  k_fc1<<<4096 * 8, 128, 0, stream>>>(WtF, wpair, wcnt, d_in[6], h, flag, 1);
  k_sel<<<1024, 256, 0, stream>>>(h, d_in[7], d_in[8], d_in[9], d_out, flag);
}